// Round 10
// baseline (22619.389 us; speedup 1.0000x reference)
//
#include <hip/hip_runtime.h>
#include <cstdint>
#include <cstddef>

#define VOCAB_N 50257
#define NPAD    50304          // padded row stride for logits (393 * 128)
#define DIM     1024
#define BSZ_N   32
#define BEAM_N  4
#define BB      128            // BSZ * BEAM
#define L_N     66             // MAXLEN + 2
#define SLEN_N  65             // MAXLEN + 1
#define MAXLEN_N 64
#define PAD_T   1
#define EOS_T   2
#define NEGV    (-1e9f)
#define SENTV   (-3.402823466e38f)
#define PW_BLOCK 128
#define HSPLIT  25128          // numpy tree root split: L=(50257>>1)-((50257>>1)&7)

typedef unsigned long long u64;
typedef __attribute__((ext_vector_type(8))) short bf16x8;
typedef __attribute__((ext_vector_type(4))) float f32x4;
typedef __attribute__((ext_vector_type(4))) unsigned short u16x4;

// ---------------- compile-time numpy pairwise_sum sub-trees ----------------
struct PWTree {
    int nleaf, nint, maxlev, root;
    int lstart[512], lnum[512], lslot[512];
    int eL[512], eR[512], eD[512];
    int lvl[32];
};

constexpr PWTree build_tree(int start, int n0) {
    PWTree t{};
    int fs[64] = {}, fn[64] = {}, fstt[64] = {}, fls[64] = {}, fll[64] = {};
    int tL[512] = {}, tR[512] = {}, tD[512] = {}, tLev[512] = {};
    int sp = 0, lc = 0, nc = 0, cnt = 0;
    fs[0] = start; fn[0] = n0; fstt[0] = 0; sp = 1;
    int retslot = -1, retlev = 0;
    while (sp > 0) {
        const int n = fn[sp - 1], s = fs[sp - 1], st = fstt[sp - 1];
        if (n <= PW_BLOCK) {
            t.lstart[lc] = s; t.lnum[lc] = n; t.lslot[lc] = cnt;
            retslot = cnt; retlev = 0; ++cnt; ++lc; --sp; continue;
        }
        int L = (n >> 1); L -= (L & 7);
        if (st == 0)      { fstt[sp - 1] = 1; fs[sp] = s;     fn[sp] = L;     fstt[sp] = 0; ++sp; }
        else if (st == 1) { fls[sp - 1] = retslot; fll[sp - 1] = retlev; fstt[sp - 1] = 2;
                            fs[sp] = s + L; fn[sp] = n - L; fstt[sp] = 0; ++sp; }
        else {
            const int lv = (fll[sp - 1] > retlev ? fll[sp - 1] : retlev) + 1;
            tL[nc] = fls[sp - 1]; tR[nc] = retslot; tD[nc] = cnt; tLev[nc] = lv;
            retslot = cnt; retlev = lv; ++cnt; ++nc; --sp;
        }
    }
    int maxlev = 0;
    for (int j = 0; j < nc; ++j) if (tLev[j] > maxlev) maxlev = tLev[j];
    int cl[40] = {};
    for (int j = 0; j < nc; ++j) cl[tLev[j]]++;
    int acc = 0;
    for (int v = 1; v <= maxlev; ++v) { t.lvl[v] = acc; acc += cl[v]; }
    t.lvl[maxlev + 1] = acc;
    int pos[40] = {};
    for (int v = 1; v <= maxlev; ++v) pos[v] = t.lvl[v];
    for (int j = 0; j < nc; ++j) {
        const int v = tLev[j]; const int p = pos[v]++;
        t.eL[p] = tL[j]; t.eR[p] = tR[j]; t.eD[p] = tD[j];
    }
    t.nleaf = lc; t.nint = nc; t.maxlev = maxlev; t.root = retslot;
    return t;
}

__device__ constexpr PWTree g_treeL = build_tree(0, HSPLIT);
__device__ constexpr PWTree g_treeR = build_tree(HSPLIT, VOCAB_N - HSPLIT);

// ---------------- init state ----------------
__global__ void k_init(int* __restrict__ tokens, float* __restrict__ scores,
                       int* __restrict__ fin_tok, float* __restrict__ fin_sc) {
    int i = blockIdx.x * blockDim.x + threadIdx.x;
    int st = gridDim.x * blockDim.x;
    for (int k = i; k < BB * L_N; k += st) tokens[k] = ((k % L_N) == 0) ? EOS_T : PAD_T;
    for (int k = i; k < BB * SLEN_N; k += st) scores[k] = 0.f;
    for (int k = i; k < BB * L_N; k += st) fin_tok[k] = 0;
    for (int k = i; k < BB; k += st) fin_sc[k] = NEGV;
}

// ---------------- exact 3-way bf16 split (truncation; x == b0+b1+b2 exactly) ----------------
__device__ __forceinline__ void split3(float x, unsigned short& b0,
                                       unsigned short& b1, unsigned short& b2) {
    const unsigned u0 = __float_as_uint(x);
    b0 = (unsigned short)(u0 >> 16);
    const float f0 = __uint_as_float((unsigned)b0 << 16);
    const float r1 = x - f0;                     // exact (<=16 sig bits)
    const unsigned u1 = __float_as_uint(r1);
    b1 = (unsigned short)(u1 >> 16);
    const float f1 = __uint_as_float((unsigned)b1 << 16);
    const float r2 = r1 - f1;                    // exact (<=8 sig bits)
    b2 = (unsigned short)(__float_as_uint(r2) >> 16);   // exact (8-bit value)
}

// ---------------- MFMA GEMM: 128x128 tile, 512 thr, bf16 3-split, f32 accum ----------------
#define KT 32
__global__ __launch_bounds__(512) void k_gemm(const float* __restrict__ W,
                                              const float* __restrict__ emb,
                                              const float* __restrict__ pos_emb,
                                              const int* __restrict__ tokens,
                                              float* __restrict__ logits, int step) {
    __shared__ __align__(16) unsigned short Ha[3][128][40];   // H rows [row][k], pad 40
    __shared__ __align__(16) unsigned short Wb[3][128][40];   // W cols [col][k], pad 40
    const int tid = threadIdx.x;
    const int n0 = blockIdx.x * 128;
    const bool full = (n0 + 128 <= VOCAB_N);

    const int lane = tid & 63, wid = tid >> 6;
    const int wr = wid >> 1;          // 0..3: rows wr*32..+31
    const int wc = wid & 1;           // 0..1: cols wc*64..+63
    const int la = lane & 15, g = lane >> 4;

    // staging assignments
    const int hrow = tid & 127;                       // H row for this thread
    const int hkq  = tid >> 7;                        // 0..3 (and +4 for second quad)
    const int tokH = tokens[hrow * L_N + step];
    const float* eprow = emb + (size_t)tokH * DIM;
    const float* pprow = pos_emb + (size_t)step * DIM;
    const int wcq = tid & 31;                         // W col-quad (cols wcq*4..+3)
    const int wk0 = tid >> 5;                         // W k (0..15, and +16)

    f32x4 acc[2][4];
#pragma unroll
    for (int mf = 0; mf < 2; ++mf)
#pragma unroll
        for (int nf = 0; nf < 4; ++nf)
#pragma unroll
            for (int j = 0; j < 4; ++j) acc[mf][nf][j] = 0.f;

    for (int k0 = 0; k0 < DIM; k0 += KT) {
        // ---- stage W: 32k x 128cols, transposed to [col][k] ----
#pragma unroll
        for (int qq = 0; qq < 2; ++qq) {
            const int kk = wk0 + qq * 16;
            const int c0 = wcq * 4;
            const float* wp = W + (size_t)(k0 + kk) * VOCAB_N + n0 + c0;
            float wv[4];
            if (full) {
                const float4 t4 = *(const float4*)wp;
                wv[0] = t4.x; wv[1] = t4.y; wv[2] = t4.z; wv[3] = t4.w;
            } else {
#pragma unroll
                for (int d = 0; d < 4; ++d)
                    wv[d] = (n0 + c0 + d < VOCAB_N) ? wp[d] : 0.f;
            }
#pragma unroll
            for (int d = 0; d < 4; ++d) {
                unsigned short b0, b1, b2;
                split3(wv[d], b0, b1, b2);
                Wb[0][c0 + d][kk] = b0;
                Wb[1][c0 + d][kk] = b1;
                Wb[2][c0 + d][kk] = b2;
            }
        }
        // ---- stage H: 128rows x 32k, [row][k] (same single-rounded emb+pos values) ----
#pragma unroll
        for (int qq = 0; qq < 2; ++qq) {
            const int kq = hkq + qq * 4;              // 0..7
            const float4 e0 = *(const float4*)(eprow + k0 + kq * 4);
            const float4 p0 = *(const float4*)(pprow + k0 + kq * 4);
            const float hv[4] = {e0.x + p0.x, e0.y + p0.y, e0.z + p0.z, e0.w + p0.w};
            u16x4 o0, o1, o2;
#pragma unroll
            for (int d = 0; d < 4; ++d) {
                unsigned short b0, b1, b2;
                split3(hv[d], b0, b1, b2);
                o0[d] = b0; o1[d] = b1; o2[d] = b2;
            }
            *(u16x4*)&Ha[0][hrow][kq * 4] = o0;
            *(u16x4*)&Ha[1][hrow][kq * 4] = o1;
            *(u16x4*)&Ha[2][hrow][kq * 4] = o2;
        }
        __syncthreads();

        // ---- compute: per wave 32 rows x 64 cols, 48 MFMA ----
        bf16x8 af[2][3];
#pragma unroll
        for (int mf = 0; mf < 2; ++mf)
#pragma unroll
            for (int s = 0; s < 3; ++s)
                af[mf][s] = *(const bf16x8*)&Ha[s][wr * 32 + mf * 16 + la][g * 8];
#pragma unroll
        for (int nf = 0; nf < 4; ++nf) {
            const int c = wc * 64 + nf * 16 + la;
            const bf16x8 b0 = *(const bf16x8*)&Wb[0][c][g * 8];
            const bf16x8 b1 = *(const bf16x8*)&Wb[1][c][g * 8];
            const bf16x8 b2 = *(const bf16x8*)&Wb[2][c][g * 8];
#pragma unroll
            for (int mf = 0; mf < 2; ++mf) {
                f32x4 cc = acc[mf][nf];
                cc = __builtin_amdgcn_mfma_f32_16x16x32_bf16(af[mf][0], b0, cc, 0, 0, 0);
                cc = __builtin_amdgcn_mfma_f32_16x16x32_bf16(af[mf][0], b1, cc, 0, 0, 0);
                cc = __builtin_amdgcn_mfma_f32_16x16x32_bf16(af[mf][1], b0, cc, 0, 0, 0);
                cc = __builtin_amdgcn_mfma_f32_16x16x32_bf16(af[mf][0], b2, cc, 0, 0, 0);
                cc = __builtin_amdgcn_mfma_f32_16x16x32_bf16(af[mf][1], b1, cc, 0, 0, 0);
                cc = __builtin_amdgcn_mfma_f32_16x16x32_bf16(af[mf][2], b0, cc, 0, 0, 0);
                acc[mf][nf] = cc;
            }
        }
        __syncthreads();
    }

    // ---- epilogue: C/D mapping col=lane&15, row=(lane>>4)*4+reg (HW-verified) ----
#pragma unroll
    for (int mf = 0; mf < 2; ++mf) {
        const int row = wr * 32 + mf * 16 + g * 4;
#pragma unroll
        for (int nf = 0; nf < 4; ++nf) {
            const int col = n0 + wc * 64 + nf * 16 + la;
#pragma unroll
            for (int j = 0; j < 4; ++j)
                logits[(size_t)(row + j) * NPAD + col] = acc[mf][nf][j];
        }
    }
}

// ---------------- packed (x, idx) keys: strict total order, stable ties ----------------
__device__ __forceinline__ unsigned sortable_f32(float x) {
    unsigned u = __float_as_uint(x);
    return (u & 0x80000000u) ? ~u : (u | 0x80000000u);
}
__device__ __forceinline__ float unsort_f32(unsigned s) {
    unsigned u = (s & 0x80000000u) ? (s & 0x7fffffffu) : ~s;
    return __uint_as_float(u);
}
__device__ __forceinline__ u64 pack_key(float x, int tk) {
    return ((u64)sortable_f32(x) << 32) | (unsigned)(VOCAB_N - tk);
}
__device__ __forceinline__ void insk16(u64 k, u64 lst[16]) {
#pragma unroll
    for (int p = 0; p < 16; ++p) {
        if (k > lst[p]) { u64 o = lst[p]; lst[p] = k; k = o; }
    }
}
__device__ __forceinline__ u64 wave_max_u64(u64 v) {
#pragma unroll
    for (int o = 32; o > 0; o >>= 1) {
        u64 w = __shfl_xor(v, o, 64);
        if (w > v) v = w;
    }
    return v;
}

// ---------------- pass 1: per half-row max (incl PAD) + top-16 (excl PAD) ----------------
#define RT_THR 512
__global__ __launch_bounds__(RT_THR) void k_rowscan(const float* __restrict__ logits,
                                                    float* __restrict__ halfmax,
                                                    u64* __restrict__ htop) {
    const int hb = blockIdx.x;            // 0..255
    const int row = hb >> 1, half = hb & 1;
    const int tid = threadIdx.x;
    const int lane = tid & 63, wid = tid >> 6;   // 8 waves
    const float* x = logits + (size_t)row * NPAD;
    const int lo = half ? HSPLIT : 0;
    const int hi = half ? VOCAB_N : HSPLIT;

    u64 lst[16];
#pragma unroll
    for (int p = 0; p < 16; ++p) lst[p] = 0ULL;
    float mAll = SENTV;
    for (int v = lo + tid * 4; v + 3 < hi; v += RT_THR * 4) {
        const float4 t = *(const float4*)(x + v);
        mAll = fmaxf(mAll, fmaxf(fmaxf(t.x, t.y), fmaxf(t.z, t.w)));
        const float va[4] = {t.x, t.y, t.z, t.w};
#pragma unroll
        for (int u = 0; u < 4; ++u) {
            const int tk = v + u;
            if (tk == PAD_T) continue;
            const u64 key = pack_key(va[u], tk);
            if (key > lst[15]) insk16(key, lst);
        }
    }
    if (half == 1 && tid == 0) {          // tail element 50256
        const int tk = VOCAB_N - 1;
        mAll = fmaxf(mAll, x[tk]);
        const u64 key = pack_key(x[tk], tk);
        if (key > lst[15]) insk16(key, lst);
    }

    // wave max
#pragma unroll
    for (int o = 32; o > 0; o >>= 1) mAll = fmaxf(mAll, __shfl_xor(mAll, o, 64));
    __shared__ float smx[8];
    if (lane == 0) smx[wid] = mAll;

    // per-wave top-16 tournament
    __shared__ u64 wtop[8][16];
    for (int pass = 0; pass < 16; ++pass) {
        const u64 cand = lst[0];
        const u64 mx = wave_max_u64(cand);
        const u64 ball = __ballot(cand == mx);
        const int first = __ffsll((u64)ball) - 1;
        if (lane == first) {
#pragma unroll
            for (int p = 0; p < 15; ++p) lst[p] = lst[p + 1];
            lst[15] = 0ULL;
        }
        if (lane == 0) wtop[wid][pass] = mx;
    }
    __syncthreads();

    // wave 0 merges 8x16 = 128 keys -> top-16
    __shared__ u64 sfin[16];
    if (tid < 64) {
        u64 a = wtop[tid >> 3][(tid & 7) * 2];      // descending pair: a >= b
        u64 b = wtop[tid >> 3][(tid & 7) * 2 + 1];
        for (int pass = 0; pass < 16; ++pass) {
            const u64 mx = wave_max_u64(a);
            const u64 ball = __ballot(a == mx);
            const int first = __ffsll((u64)ball) - 1;
            if (tid == first) { a = b; b = 0ULL; }
            if (tid == 0) sfin[pass] = mx;
        }
    }
    __syncthreads();
    if (tid == 0)
        halfmax[hb] = fmaxf(fmaxf(fmaxf(smx[0], smx[1]), fmaxf(smx[2], smx[3])),
                            fmaxf(fmaxf(smx[4], smx[5]), fmaxf(smx[6], smx[7])));
    if (tid < 16) htop[hb * 16 + tid] = sfin[tid];
}

// ---------------- pass 2: numpy-exact pairwise exp-sum over the half sub-tree ----------------
__global__ __launch_bounds__(RT_THR) void k_rowexp(const float* __restrict__ logits,
                                                   const float* __restrict__ halfmax,
                                                   float* __restrict__ halfsum) {
    const int hb = blockIdx.x;
    const int row = hb >> 1, half = hb & 1;
    const int tid = threadIdx.x;
    const float* x = logits + (size_t)row * NPAD;
    const float mrow = fmaxf(halfmax[row * 2], halfmax[row * 2 + 1]);   // whole-row max
    const PWTree& T = half ? g_treeR : g_treeL;

    __shared__ float slot[1024];
    for (int leaf = tid; leaf < T.nleaf; leaf += RT_THR) {
        const int s = T.lstart[leaf];
        const int n = T.lnum[leaf];
        float res;
        if (n < 8) {
            res = 0.f;
            for (int i = 0; i < n; ++i) res += expf(x[s + i] - mrow);
        } else {
            float r0 = expf(x[s + 0] - mrow), r1 = expf(x[s + 1] - mrow);
            float r2 = expf(x[s + 2] - mrow), r3 = expf(x[s + 3] - mrow);
            float r4 = expf(x[s + 4] - mrow), r5 = expf(x[s + 5] - mrow);
            float r6 = expf(x[s + 6] - mrow), r7 = expf(x[s + 7] - mrow);
            int i = 8;
            const int lim = n - (n & 7);
            for (; i < lim; i += 8) {
                r0 += expf(x[s + i + 0] - mrow); r1 += expf(x[s + i + 1] - mrow);
                r2 += expf(x[s + i + 2] - mrow); r3 += expf(x[s + i + 3] - mrow);
                r4 += expf(x[s + i + 4] - mrow); r5 += expf(x[s + i + 5] - mrow);
                r6 += expf(x[s + i + 6] - mrow); r7 += expf(x[s + i + 7] - mrow);
            }
            res = ((r0 + r1) + (r2 + r3)) + ((r4 + r5) + (r6 + r7));
            for (; i < n; ++i) res += expf(x[s + i] - mrow);
        }
        slot[T.lslot[leaf]] = res;
    }
    __syncthreads();
    for (int lev = 1; lev <= T.maxlev; ++lev) {
        for (int j = T.lvl[lev] + tid; j < T.lvl[lev + 1]; j += RT_THR)
            slot[T.eD[j]] = slot[T.eL[j]] + slot[T.eR[j]];
        __syncthreads();
    }
    if (tid == 0) halfsum[hb] = slot[T.root];
}

// ---------------- per-sentence: merge halves + top-8 + literal bookkeeping ----------------
__global__ __launch_bounds__(256) void k_beam(const u64* __restrict__ htop,
                                              const float* __restrict__ halfmax,
                                              const float* __restrict__ halfsum,
                                              int* __restrict__ tokens,
                                              float* __restrict__ scores,
                                              int* __restrict__ fin_tok,
                                              float* __restrict__ fin_sc,
                                              int step) {
    const int sent = blockIdx.x;
    const int tid = threadIdx.x;
    const int rN = (step == 0) ? 1 : BEAM_N;

    // load 4 rows x 2 halves x 16 keys
    __shared__ u64 keys[4][32];
    for (int e = tid; e < 128; e += 256) {
        const int r = e >> 5, i = e & 31;
        keys[r][i] = htop[((sent * BEAM_N + r) * 2 + (i >> 4)) * 16 + (i & 15)];
    }
    __syncthreads();

    // two-pointer merge of the two desc-sorted 16-lists -> row top-16 (keys strictly distinct)
    __shared__ u64 merged[4][16];
    if (tid < 4) {
        int ia = 0, ib = 0;
        for (int o = 0; o < 16; ++o) {
            const u64 a = (ia < 16) ? keys[tid][ia] : 0ULL;
            const u64 b = (ib < 16) ? keys[tid][16 + ib] : 0ULL;
            const bool ta = a > b;
            merged[tid][o] = ta ? a : b;
            ia += ta ? 1 : 0; ib += ta ? 0 : 1;
        }
    }
    __syncthreads();

    __shared__ float bval[64]; __shared__ int bflat[64];
    if (tid < 16 * rN) {
        const int r = tid >> 4, j = tid & 15;
        const int row = sent * BEAM_N + r;
        const float rm = fmaxf(halfmax[row * 2], halfmax[row * 2 + 1]);
        const float rl = (float)log((double)(halfsum[row * 2] + halfsum[row * 2 + 1]));
        const float prev = (step == 0) ? 0.f : scores[row * SLEN_N + step - 1];
        const u64 k = merged[r][j];
        const float xv = unsort_f32((unsigned)(k >> 32));
        const int   tk = VOCAB_N - (int)(k & 0xFFFFFFFFu);
        bval[tid]  = ((xv - rm) - rl) + prev;   // exact ref association
        bflat[tid] = r * VOCAB_N + tk;
    }
    __syncthreads();
    __shared__ float cand_sc[8]; __shared__ int cand_flat[8];
    if (tid == 0) {
        const int nC = 16 * rN;
        for (int pass = 0; pass < 8; ++pass) {
            float bv = SENTV; int bi = 0x7fffffff; int bs = -1;
            for (int k = 0; k < nC; ++k) {
                const float v = bval[k]; const int ix = bflat[k];
                if (v > bv || (v == bv && ix < bi)) { bv = v; bi = ix; bs = k; }
            }
            cand_sc[pass] = bv; cand_flat[pass] = bi;
            bval[bs] = SENTV; bflat[bs] = 0x7fffffff;
        }
    }
    __syncthreads();

    __shared__ int   cur_tok[BEAM_N * L_N];
    __shared__ int   cur_fin[BEAM_N * L_N];
    __shared__ float cur_sc[BEAM_N * SLEN_N];
    for (int e = tid; e < BEAM_N * L_N; e += 256) {
        cur_tok[e] = tokens[sent * (BEAM_N * L_N) + e];
        cur_fin[e] = fin_tok[sent * (BEAM_N * L_N) + e];
    }
    for (int e = tid; e < BEAM_N * SLEN_N; e += 256)
        cur_sc[e] = scores[sent * (BEAM_N * SLEN_N) + e];
    __syncthreads();

    __shared__ int   tmp_fin[BEAM_N * L_N];
    __shared__ int   tmp_tok[BEAM_N * L_N];
    __shared__ float tmp_sc[BEAM_N * SLEN_N];
    __shared__ float nfin_s[BEAM_N];
    if (tid == 0) {
        int cb[8], ct[8];
#pragma unroll
        for (int j = 0; j < 8; ++j) {
            cb[j] = cand_flat[j] / VOCAB_N;
            ct[j] = cand_flat[j] % VOCAB_N;
        }
        float allsc[8];
#pragma unroll
        for (int j = 0; j < 4; ++j) allsc[j] = fin_sc[sent * BEAM_N + j];
#pragma unroll
        for (int j = 0; j < 4; ++j)
            allsc[4 + j] = (ct[j] == EOS_T) ? (cand_sc[j] / (float)(step + 1)) : NEGV;
        int fsel[4]; float nfin[4];
        bool used[8] = {false,false,false,false,false,false,false,false};
#pragma unroll
        for (int b = 0; b < 4; ++b) {
            int best = -1; float bvv = 0.f;
#pragma unroll
            for (int j = 0; j < 8; ++j) {
                if (used[j]) continue;
                if (best < 0 || allsc[j] > bvv) { best = j; bvv = allsc[j]; }
            }
            used[best] = true; fsel[b] = best; nfin[b] = bvv;
        }
#pragma unroll
        for (int b = 0; b < 4; ++b) {
            const int s = fsel[b];
            if (s < 4) {
                for (int p = 0; p < L_N; ++p) tmp_fin[b * L_N + p] = cur_fin[s * L_N + p];
            } else {
                const int bm = cb[s - 4];
                for (int p = 0; p < L_N; ++p)
                    tmp_fin[b * L_N + p] = (p == step + 1) ? EOS_T : cur_tok[bm * L_N + p];
            }
        }
        int ab[4], atk[4]; float asc[4]; int na = 0;
#pragma unroll
        for (int j = 0; j < 8; ++j) {
            if (na < 4 && ct[j] != EOS_T) { ab[na] = cb[j]; atk[na] = ct[j]; asc[na] = cand_sc[j]; ++na; }
        }
#pragma unroll
        for (int b = 0; b < 4; ++b) {
            const int bm = ab[b];
            for (int p = 0; p < L_N; ++p)
                tmp_tok[b * L_N + p] = (p == step + 1) ? atk[b] : cur_tok[bm * L_N + p];
            for (int p = 0; p < SLEN_N; ++p)
                tmp_sc[b * SLEN_N + p] = (p == step) ? asc[b] : cur_sc[bm * SLEN_N + p];
        }
#pragma unroll
        for (int b = 0; b < 4; ++b) nfin_s[b] = nfin[b];
    }
    __syncthreads();

    for (int e = tid; e < BEAM_N * L_N; e += 256) {
        fin_tok[sent * (BEAM_N * L_N) + e] = tmp_fin[e];
        tokens[sent * (BEAM_N * L_N) + e]  = tmp_tok[e];
    }
    for (int e = tid; e < BEAM_N * SLEN_N; e += 256)
        scores[sent * (BEAM_N * SLEN_N) + e] = tmp_sc[e];
    if (tid < 4) fin_sc[sent * BEAM_N + tid] = nfin_s[tid];
}

// ---------------- final forced-EOS merge + output write ----------------
__global__ __launch_bounds__(256) void k_final(const float* __restrict__ logits,
                                               const float* __restrict__ halfmax,
                                               const float* __restrict__ halfsum,
                                               const int* __restrict__ tokens,
                                               const float* __restrict__ scores,
                                               const int* __restrict__ fin_tok,
                                               const float* __restrict__ fin_sc,
                                               float* __restrict__ out) {
    const int sent = blockIdx.x;
    const int tid = threadIdx.x;
    __shared__ int fsel_s[4]; __shared__ float nfin_s[4];
    if (tid == 0) {
        float allsc[8];
#pragma unroll
        for (int r = 0; r < 4; ++r) {
            const int row = sent * BEAM_N + r;
            const float rm = fmaxf(halfmax[row * 2], halfmax[row * 2 + 1]);
            const float rl = (float)log((double)(halfsum[row * 2] + halfsum[row * 2 + 1]));
            const float lpE = ((logits[(size_t)row * NPAD + EOS_T] - rm) - rl);
            allsc[r] = fin_sc[sent * BEAM_N + r];
            allsc[4 + r] = (scores[row * SLEN_N + (MAXLEN_N - 1)] + lpE) / 65.0f;
        }
        bool used[8] = {false,false,false,false,false,false,false,false};
#pragma unroll
        for (int b = 0; b < 4; ++b) {
            int best = -1; float bvv = 0.f;
#pragma unroll
            for (int j = 0; j < 8; ++j) {
                if (used[j]) continue;
                if (best < 0 || allsc[j] > bvv) { best = j; bvv = allsc[j]; }
            }
            used[best] = true; fsel_s[b] = best; nfin_s[b] = bvv;
        }
    }
    __syncthreads();
    for (int e = tid; e < BEAM_N * L_N; e += 256) {
        const int b = e / L_N, p = e % L_N;
        const int s = fsel_s[b]; int valt;
        if (s < 4) {
            valt = fin_tok[(sent * BEAM_N + s) * L_N + p];
        } else {
            const int r = s - 4;
            valt = (p == MAXLEN_N + 1) ? EOS_T : tokens[(sent * BEAM_N + r) * L_N + p];
        }
        out[(size_t)(sent * BEAM_N + b) * L_N + p] = (float)valt;
    }
    if (tid < 4) out[BSZ_N * BEAM_N * L_N + sent * BEAM_N + tid] = nfin_s[tid];
}

extern "C" void kernel_launch(void* const* d_in, const int* in_sizes, int n_in,
                              void* d_out, int out_size, void* d_ws, size_t ws_size,
                              hipStream_t stream) {
    const float* emb = (const float*)d_in[0];
    const float* W   = (const float*)d_in[1];
    const float* pos = (const float*)d_in[2];
    float* out = (float*)d_out;

    char* w = (char*)d_ws;
    float* logits  = (float*)w;  w += (size_t)BB * NPAD * 4;       // 25.76 MB
    float* halfmax = (float*)w;  w += BB * 2 * 4;
    float* halfsum = (float*)w;  w += BB * 2 * 4;
    u64*   htop    = (u64*)w;    w += (size_t)BB * 2 * 16 * 8;     // 32 KB
    int*   tokens  = (int*)w;    w += BB * L_N * 4;
    float* scores  = (float*)w;  w += BB * SLEN_N * 4;
    int*   ftok    = (int*)w;    w += BB * L_N * 4;
    float* fsc     = (float*)w;  w += BB * 4;

    k_init<<<32, 256, 0, stream>>>(tokens, scores, ftok, fsc);
    for (int s = 0; s < MAXLEN_N; ++s) {
        k_gemm<<<NPAD / 128, 512, 0, stream>>>(W, emb, pos, tokens, logits, s);
        k_rowscan<<<BB * 2, RT_THR, 0, stream>>>(logits, halfmax, htop);
        k_rowexp<<<BB * 2, RT_THR, 0, stream>>>(logits, halfmax, halfsum);
        k_beam<<<BSZ_N, 256, 0, stream>>>(htop, halfmax, halfsum, tokens, scores, ftok, fsc, s);
    }
    k_gemm<<<NPAD / 128, 512, 0, stream>>>(W, emb, pos, tokens, logits, MAXLEN_N);
    k_rowscan<<<BB * 2, RT_THR, 0, stream>>>(logits, halfmax, htop);
    k_rowexp<<<BB * 2, RT_THR, 0, stream>>>(logits, halfmax, halfsum);
    k_final<<<BSZ_N, 256, 0, stream>>>(logits, halfmax, halfsum, tokens, scores, ftok, fsc, out);
}

// Round 11
// 13952.837 us; speedup vs baseline: 1.6211x; 1.6211x over previous
//
#include <hip/hip_runtime.h>
#include <cstdint>
#include <cstddef>

#define VOCAB_N 50257
#define NPAD    50304          // padded row stride for logits (393 * 128)
#define DIM     1024
#define BSZ_N   32
#define BEAM_N  4
#define BB      128            // BSZ * BEAM
#define L_N     66             // MAXLEN + 2
#define SLEN_N  65             // MAXLEN + 1
#define MAXLEN_N 64
#define PAD_T   1
#define EOS_T   2
#define NEGV    (-1e9f)
#define SENTV   (-3.402823466e38f)
#define PW_BLOCK 128
#define HSPLIT  25128          // numpy tree root split: L=(50257>>1)-((50257>>1)&7)

typedef unsigned long long u64;
typedef __attribute__((ext_vector_type(8))) _Float16 f16x8;
typedef __attribute__((ext_vector_type(4))) _Float16 f16x4;
typedef __attribute__((ext_vector_type(4))) float f32x4;

// ---------------- compile-time numpy pairwise_sum sub-trees ----------------
struct PWTree {
    int nleaf, nint, maxlev, root;
    int lstart[512], lnum[512], lslot[512];
    int eL[512], eR[512], eD[512];
    int lvl[32];
};

constexpr PWTree build_tree(int start, int n0) {
    PWTree t{};
    int fs[64] = {}, fn[64] = {}, fstt[64] = {}, fls[64] = {}, fll[64] = {};
    int tL[512] = {}, tR[512] = {}, tD[512] = {}, tLev[512] = {};
    int sp = 0, lc = 0, nc = 0, cnt = 0;
    fs[0] = start; fn[0] = n0; fstt[0] = 0; sp = 1;
    int retslot = -1, retlev = 0;
    while (sp > 0) {
        const int n = fn[sp - 1], s = fs[sp - 1], st = fstt[sp - 1];
        if (n <= PW_BLOCK) {
            t.lstart[lc] = s; t.lnum[lc] = n; t.lslot[lc] = cnt;
            retslot = cnt; retlev = 0; ++cnt; ++lc; --sp; continue;
        }
        int L = (n >> 1); L -= (L & 7);
        if (st == 0)      { fstt[sp - 1] = 1; fs[sp] = s;     fn[sp] = L;     fstt[sp] = 0; ++sp; }
        else if (st == 1) { fls[sp - 1] = retslot; fll[sp - 1] = retlev; fstt[sp - 1] = 2;
                            fs[sp] = s + L; fn[sp] = n - L; fstt[sp] = 0; ++sp; }
        else {
            const int lv = (fll[sp - 1] > retlev ? fll[sp - 1] : retlev) + 1;
            tL[nc] = fls[sp - 1]; tR[nc] = retslot; tD[nc] = cnt; tLev[nc] = lv;
            retslot = cnt; retlev = lv; ++cnt; ++nc; --sp;
        }
    }
    int maxlev = 0;
    for (int j = 0; j < nc; ++j) if (tLev[j] > maxlev) maxlev = tLev[j];
    int cl[40] = {};
    for (int j = 0; j < nc; ++j) cl[tLev[j]]++;
    int acc = 0;
    for (int v = 1; v <= maxlev; ++v) { t.lvl[v] = acc; acc += cl[v]; }
    t.lvl[maxlev + 1] = acc;
    int pos[40] = {};
    for (int v = 1; v <= maxlev; ++v) pos[v] = t.lvl[v];
    for (int j = 0; j < nc; ++j) {
        const int v = tLev[j]; const int p = pos[v]++;
        t.eL[p] = tL[j]; t.eR[p] = tR[j]; t.eD[p] = tD[j];
    }
    t.nleaf = lc; t.nint = nc; t.maxlev = maxlev; t.root = retslot;
    return t;
}

__device__ constexpr PWTree g_treeL = build_tree(0, HSPLIT);
__device__ constexpr PWTree g_treeR = build_tree(HSPLIT, VOCAB_N - HSPLIT);

// ---------------- sortable f32 encoding ----------------
__device__ __forceinline__ unsigned sortable_f32(float x) {
    unsigned u = __float_as_uint(x);
    return (u & 0x80000000u) ? ~u : (u | 0x80000000u);
}
__device__ __forceinline__ float unsort_f32(unsigned s) {
    unsigned u = (s & 0x80000000u) ? (s & 0x7fffffffu) : ~s;
    return __uint_as_float(u);
}

// ---------------- init state ----------------
__global__ void k_init(int* __restrict__ tokens, float* __restrict__ scores,
                       int* __restrict__ fin_tok, float* __restrict__ fin_sc,
                       unsigned* __restrict__ rmax_u) {
    int i = blockIdx.x * blockDim.x + threadIdx.x;
    int st = gridDim.x * blockDim.x;
    for (int k = i; k < BB * L_N; k += st) tokens[k] = ((k % L_N) == 0) ? EOS_T : PAD_T;
    for (int k = i; k < BB * SLEN_N; k += st) scores[k] = 0.f;
    for (int k = i; k < BB * L_N; k += st) fin_tok[k] = 0;
    for (int k = i; k < BB; k += st) { fin_sc[k] = NEGV; rmax_u[k] = 0u; }
}

// ---------------- exact scaled 2-way f16 split: x*4096 == h0 + h1 + O(2^-24 x) ----------------
__device__ __forceinline__ void split2(float x, _Float16& h0, _Float16& h1) {
    const float xs = x * 4096.f;       // exact (power of 2)
    h0 = (_Float16)xs;                 // RN
    const float r = xs - (float)h0;    // exact
    h1 = (_Float16)r;                  // RN
}

// ---------------- MFMA GEMM: 128x128 tile, 512 thr, f16 2-plane scaled split ----------------
#define KT 32
__global__ __launch_bounds__(512) void k_gemm(const float* __restrict__ W,
                                              const float* __restrict__ emb,
                                              const float* __restrict__ pos_emb,
                                              const int* __restrict__ tokens,
                                              float* __restrict__ logits,
                                              unsigned* __restrict__ rmax_u, int step) {
    __shared__ __align__(16) _Float16 Ha[2][128][40];   // 20 KB
    __shared__ __align__(16) _Float16 Wb[2][128][40];   // 20 KB
    __shared__ unsigned smax[128];
    const int tid = threadIdx.x;
    const int n0 = blockIdx.x * 128;
    const bool full = (n0 + 128 <= VOCAB_N);

    const int lane = tid & 63, wid = tid >> 6;
    const int wr = wid >> 1;          // 0..3: rows wr*32..+31
    const int wc = wid & 1;           // 0..1: cols wc*64..+63
    const int la = lane & 15, g = lane >> 4;

    const int hrow = tid & 127;                       // H staging row
    const int hkq  = tid >> 7;                        // 0..3
    const int tokH = tokens[hrow * L_N + step];
    const float* eprow = emb + (size_t)tokH * DIM;
    const float* pprow = pos_emb + (size_t)step * DIM;
    const int wcq = tid & 31;                         // W staging col (stride-32 groups)
    const int wk  = tid >> 5;                         // W staging k (0..15, +16)

    if (tid < 128) smax[tid] = 0u;

    f32x4 acc[2][4];
#pragma unroll
    for (int mf = 0; mf < 2; ++mf)
#pragma unroll
        for (int nf = 0; nf < 4; ++nf)
#pragma unroll
            for (int j = 0; j < 4; ++j) acc[mf][nf][j] = 0.f;

    for (int k0 = 0; k0 < DIM; k0 += KT) {
        // ---- stage W: [col][k], cols in stride-32 groups (4-way write conflict max) ----
#pragma unroll
        for (int d = 0; d < 4; ++d) {
            const int c = wcq + 32 * d;
#pragma unroll
            for (int qq = 0; qq < 2; ++qq) {
                const int kk = wk + 16 * qq;
                float wv = 0.f;
                if (full || (n0 + c < VOCAB_N))
                    wv = W[(size_t)(k0 + kk) * VOCAB_N + n0 + c];
                _Float16 b0, b1;
                split2(wv, b0, b1);
                Wb[0][c][kk] = b0;
                Wb[1][c][kk] = b1;
            }
        }
        // ---- stage H: [row][k] (same single-rounded emb+pos values) ----
#pragma unroll
        for (int qq = 0; qq < 2; ++qq) {
            const int kq = hkq + 4 * qq;              // 0..7
            const float4 e0 = *(const float4*)(eprow + k0 + kq * 4);
            const float4 p0 = *(const float4*)(pprow + k0 + kq * 4);
            const float hv[4] = {e0.x + p0.x, e0.y + p0.y, e0.z + p0.z, e0.w + p0.w};
            f16x4 o0, o1;
#pragma unroll
            for (int d = 0; d < 4; ++d) {
                _Float16 a0, a1;
                split2(hv[d], a0, a1);
                o0[d] = a0; o1[d] = a1;
            }
            *(f16x4*)&Ha[0][hrow][kq * 4] = o0;
            *(f16x4*)&Ha[1][hrow][kq * 4] = o1;
        }
        __syncthreads();

        // ---- compute: per wave 32 rows x 64 cols, 24 MFMA ----
        f16x8 af[2][2];
#pragma unroll
        for (int mf = 0; mf < 2; ++mf)
#pragma unroll
            for (int p = 0; p < 2; ++p)
                af[mf][p] = *(const f16x8*)&Ha[p][wr * 32 + mf * 16 + la][g * 8];
#pragma unroll
        for (int nf = 0; nf < 4; ++nf) {
            const int c = wc * 64 + nf * 16 + la;
            const f16x8 b0 = *(const f16x8*)&Wb[0][c][g * 8];
            const f16x8 b1 = *(const f16x8*)&Wb[1][c][g * 8];
#pragma unroll
            for (int mf = 0; mf < 2; ++mf) {
                f32x4 cc = acc[mf][nf];
                cc = __builtin_amdgcn_mfma_f32_16x16x32_f16(af[mf][0], b0, cc, 0, 0, 0);
                cc = __builtin_amdgcn_mfma_f32_16x16x32_f16(af[mf][0], b1, cc, 0, 0, 0);
                cc = __builtin_amdgcn_mfma_f32_16x16x32_f16(af[mf][1], b0, cc, 0, 0, 0);
                acc[mf][nf] = cc;
            }
        }
        __syncthreads();
    }

    // ---- epilogue: unscale (exact 2^-24), store, row-max atomics ----
#pragma unroll
    for (int mf = 0; mf < 2; ++mf) {
        const int row = wr * 32 + mf * 16 + g * 4;
        float rmx[4] = {SENTV, SENTV, SENTV, SENTV};
#pragma unroll
        for (int nf = 0; nf < 4; ++nf) {
            const int col = n0 + wc * 64 + nf * 16 + la;
#pragma unroll
            for (int j = 0; j < 4; ++j) {
                const float v = acc[mf][nf][j] * 0x1p-24f;
                logits[(size_t)(row + j) * NPAD + col] = v;
                rmx[j] = fmaxf(rmx[j], v);
            }
        }
#pragma unroll
        for (int j = 0; j < 4; ++j) {
            float v = rmx[j];
            v = fmaxf(v, __shfl_xor(v, 1, 64));
            v = fmaxf(v, __shfl_xor(v, 2, 64));
            v = fmaxf(v, __shfl_xor(v, 4, 64));
            v = fmaxf(v, __shfl_xor(v, 8, 64));
            if (la == 0) atomicMax(&smax[row + j], sortable_f32(v));
        }
    }
    __syncthreads();
    if (tid < 128) atomicMax(&rmax_u[tid], smax[tid]);
}

// ---------------- packed (x, idx) keys ----------------
__device__ __forceinline__ u64 pack_key(float x, int tk) {
    return ((u64)sortable_f32(x) << 32) | (unsigned)(VOCAB_N - tk);
}
__device__ __forceinline__ void insk16(u64 k, u64 lst[16]) {
#pragma unroll
    for (int p = 0; p < 16; ++p) {
        if (k > lst[p]) { u64 o = lst[p]; lst[p] = k; k = o; }
    }
}
__device__ __forceinline__ u64 wave_max_u64(u64 v) {
#pragma unroll
    for (int o = 32; o > 0; o >>= 1) {
        u64 w = __shfl_xor(v, o, 64);
        if (w > v) v = w;
    }
    return v;
}

// ---------------- fused per-half: top-16 (excl PAD) + numpy-exact pairwise exp-sum ----------------
#define RT_THR 512
__global__ __launch_bounds__(RT_THR) void k_scanexp(const float* __restrict__ logits,
                                                    const unsigned* __restrict__ rmax_u,
                                                    u64* __restrict__ htop,
                                                    float* __restrict__ halfsum) {
    const int hb = blockIdx.x;            // 0..255
    const int row = hb >> 1, half = hb & 1;
    const int tid = threadIdx.x;
    const int lane = tid & 63, wid = tid >> 6;   // 8 waves
    const float* x = logits + (size_t)row * NPAD;
    const int lo = half ? HSPLIT : 0;
    const int hi = half ? VOCAB_N : HSPLIT;
    const float mrow = unsort_f32(rmax_u[row]);  // exact row max (from GEMM atomics)

    // ---- scan: per-thread top-16 (excluding PAD) ----
    u64 lst[16];
#pragma unroll
    for (int p = 0; p < 16; ++p) lst[p] = 0ULL;
    for (int v = lo + tid * 4; v + 3 < hi; v += RT_THR * 4) {
        const float4 t = *(const float4*)(x + v);
        const float va[4] = {t.x, t.y, t.z, t.w};
#pragma unroll
        for (int u = 0; u < 4; ++u) {
            const int tk = v + u;
            if (tk == PAD_T) continue;
            const u64 key = pack_key(va[u], tk);
            if (key > lst[15]) insk16(key, lst);
        }
    }
    if (half == 1 && tid == 0) {          // tail element 50256
        const int tk = VOCAB_N - 1;
        const u64 key = pack_key(x[tk], tk);
        if (key > lst[15]) insk16(key, lst);
    }

    // per-wave top-16 tournament
    __shared__ u64 wtop[8][16];
    for (int pass = 0; pass < 16; ++pass) {
        const u64 cand = lst[0];
        const u64 mx = wave_max_u64(cand);
        const u64 ball = __ballot(cand == mx);
        const int first = __ffsll((u64)ball) - 1;
        if (lane == first) {
#pragma unroll
            for (int p = 0; p < 15; ++p) lst[p] = lst[p + 1];
            lst[15] = 0ULL;
        }
        if (lane == 0) wtop[wid][pass] = mx;
    }
    __syncthreads();

    // wave 0 merges 8x16 = 128 keys -> top-16
    __shared__ u64 sfin[16];
    if (tid < 64) {
        u64 a = wtop[tid >> 3][(tid & 7) * 2];      // descending pair: a >= b
        u64 b = wtop[tid >> 3][(tid & 7) * 2 + 1];
        for (int pass = 0; pass < 16; ++pass) {
            const u64 mx = wave_max_u64(a);
            const u64 ball = __ballot(a == mx);
            const int first = __ffsll((u64)ball) - 1;
            if (tid == first) { a = b; b = 0ULL; }
            if (tid == 0) sfin[pass] = mx;
        }
    }

    // ---- numpy pairwise exp-sum over the half sub-tree (bit-exact proven structure) ----
    const PWTree& T = half ? g_treeR : g_treeL;
    __shared__ float slot[1024];
    for (int leaf = tid; leaf < T.nleaf; leaf += RT_THR) {
        const int s = T.lstart[leaf];
        const int n = T.lnum[leaf];
        float res;
        if (n < 8) {
            res = 0.f;
            for (int i = 0; i < n; ++i) res += expf(x[s + i] - mrow);
        } else {
            float r0 = expf(x[s + 0] - mrow), r1 = expf(x[s + 1] - mrow);
            float r2 = expf(x[s + 2] - mrow), r3 = expf(x[s + 3] - mrow);
            float r4 = expf(x[s + 4] - mrow), r5 = expf(x[s + 5] - mrow);
            float r6 = expf(x[s + 6] - mrow), r7 = expf(x[s + 7] - mrow);
            int i = 8;
            const int lim = n - (n & 7);
            for (; i < lim; i += 8) {
                r0 += expf(x[s + i + 0] - mrow); r1 += expf(x[s + i + 1] - mrow);
                r2 += expf(x[s + i + 2] - mrow); r3 += expf(x[s + i + 3] - mrow);
                r4 += expf(x[s + i + 4] - mrow); r5 += expf(x[s + i + 5] - mrow);
                r6 += expf(x[s + i + 6] - mrow); r7 += expf(x[s + i + 7] - mrow);
            }
            res = ((r0 + r1) + (r2 + r3)) + ((r4 + r5) + (r6 + r7));
            for (; i < n; ++i) res += expf(x[s + i] - mrow);
        }
        slot[T.lslot[leaf]] = res;
    }
    __syncthreads();
    for (int lev = 1; lev <= T.maxlev; ++lev) {
        for (int j = T.lvl[lev] + tid; j < T.lvl[lev + 1]; j += RT_THR)
            slot[T.eD[j]] = slot[T.eL[j]] + slot[T.eR[j]];
        __syncthreads();
    }
    if (tid == 0) halfsum[hb] = slot[T.root];
    if (tid < 16) htop[hb * 16 + tid] = sfin[tid];
}

// ---------------- per-sentence: merge halves + top-8 + literal bookkeeping ----------------
__global__ __launch_bounds__(256) void k_beam(const u64* __restrict__ htop,
                                              unsigned* __restrict__ rmax_u,
                                              const float* __restrict__ halfsum,
                                              int* __restrict__ tokens,
                                              float* __restrict__ scores,
                                              int* __restrict__ fin_tok,
                                              float* __restrict__ fin_sc,
                                              int step) {
    const int sent = blockIdx.x;
    const int tid = threadIdx.x;
    const int rN = (step == 0) ? 1 : BEAM_N;

    __shared__ u64 keys[4][32];
    for (int e = tid; e < 128; e += 256) {
        const int r = e >> 5, i = e & 31;
        keys[r][i] = htop[((sent * BEAM_N + r) * 2 + (i >> 4)) * 16 + (i & 15)];
    }
    __syncthreads();

    __shared__ u64 merged[4][16];
    if (tid < 4) {
        int ia = 0, ib = 0;
        for (int o = 0; o < 16; ++o) {
            const u64 a = (ia < 16) ? keys[tid][ia] : 0ULL;
            const u64 b = (ib < 16) ? keys[tid][16 + ib] : 0ULL;
            const bool ta = a > b;
            merged[tid][o] = ta ? a : b;
            ia += ta ? 1 : 0; ib += ta ? 0 : 1;
        }
    }
    __syncthreads();

    __shared__ float bval[64]; __shared__ int bflat[64];
    if (tid < 16 * rN) {
        const int r = tid >> 4, j = tid & 15;
        const int row = sent * BEAM_N + r;
        const float rm = unsort_f32(rmax_u[row]);
        const float rl = (float)log((double)(halfsum[row * 2] + halfsum[row * 2 + 1]));
        const float prev = (step == 0) ? 0.f : scores[row * SLEN_N + step - 1];
        const u64 k = merged[r][j];
        const float xv = unsort_f32((unsigned)(k >> 32));
        const int   tk = VOCAB_N - (int)(k & 0xFFFFFFFFu);
        bval[tid]  = ((xv - rm) - rl) + prev;   // exact ref association
        bflat[tid] = r * VOCAB_N + tk;
    }
    __syncthreads();
    __shared__ float cand_sc[8]; __shared__ int cand_flat[8];
    if (tid == 0) {
        const int nC = 16 * rN;
        for (int pass = 0; pass < 8; ++pass) {
            float bv = SENTV; int bi = 0x7fffffff; int bs = -1;
            for (int k = 0; k < nC; ++k) {
                const float v = bval[k]; const int ix = bflat[k];
                if (v > bv || (v == bv && ix < bi)) { bv = v; bi = ix; bs = k; }
            }
            cand_sc[pass] = bv; cand_flat[pass] = bi;
            bval[bs] = SENTV; bflat[bs] = 0x7fffffff;
        }
    }
    __syncthreads();

    __shared__ int   cur_tok[BEAM_N * L_N];
    __shared__ int   cur_fin[BEAM_N * L_N];
    __shared__ float cur_sc[BEAM_N * SLEN_N];
    for (int e = tid; e < BEAM_N * L_N; e += 256) {
        cur_tok[e] = tokens[sent * (BEAM_N * L_N) + e];
        cur_fin[e] = fin_tok[sent * (BEAM_N * L_N) + e];
    }
    for (int e = tid; e < BEAM_N * SLEN_N; e += 256)
        cur_sc[e] = scores[sent * (BEAM_N * SLEN_N) + e];
    __syncthreads();

    __shared__ int   tmp_fin[BEAM_N * L_N];
    __shared__ int   tmp_tok[BEAM_N * L_N];
    __shared__ float tmp_sc[BEAM_N * SLEN_N];
    __shared__ float nfin_s[BEAM_N];
    if (tid == 0) {
        int cb[8], ct[8];
#pragma unroll
        for (int j = 0; j < 8; ++j) {
            cb[j] = cand_flat[j] / VOCAB_N;
            ct[j] = cand_flat[j] % VOCAB_N;
        }
        float allsc[8];
#pragma unroll
        for (int j = 0; j < 4; ++j) allsc[j] = fin_sc[sent * BEAM_N + j];
#pragma unroll
        for (int j = 0; j < 4; ++j)
            allsc[4 + j] = (ct[j] == EOS_T) ? (cand_sc[j] / (float)(step + 1)) : NEGV;
        int fsel[4]; float nfin[4];
        bool used[8] = {false,false,false,false,false,false,false,false};
#pragma unroll
        for (int b = 0; b < 4; ++b) {
            int best = -1; float bvv = 0.f;
#pragma unroll
            for (int j = 0; j < 8; ++j) {
                if (used[j]) continue;
                if (best < 0 || allsc[j] > bvv) { best = j; bvv = allsc[j]; }
            }
            used[best] = true; fsel[b] = best; nfin[b] = bvv;
        }
#pragma unroll
        for (int b = 0; b < 4; ++b) {
            const int s = fsel[b];
            if (s < 4) {
                for (int p = 0; p < L_N; ++p) tmp_fin[b * L_N + p] = cur_fin[s * L_N + p];
            } else {
                const int bm = cb[s - 4];
                for (int p = 0; p < L_N; ++p)
                    tmp_fin[b * L_N + p] = (p == step + 1) ? EOS_T : cur_tok[bm * L_N + p];
            }
        }
        int ab[4], atk[4]; float asc[4]; int na = 0;
#pragma unroll
        for (int j = 0; j < 8; ++j) {
            if (na < 4 && ct[j] != EOS_T) { ab[na] = cb[j]; atk[na] = ct[j]; asc[na] = cand_sc[j]; ++na; }
        }
#pragma unroll
        for (int b = 0; b < 4; ++b) {
            const int bm = ab[b];
            for (int p = 0; p < L_N; ++p)
                tmp_tok[b * L_N + p] = (p == step + 1) ? atk[b] : cur_tok[bm * L_N + p];
            for (int p = 0; p < SLEN_N; ++p)
                tmp_sc[b * SLEN_N + p] = (p == step) ? asc[b] : cur_sc[bm * SLEN_N + p];
        }
#pragma unroll
        for (int b = 0; b < 4; ++b) nfin_s[b] = nfin[b];
    }
    __syncthreads();

    for (int e = tid; e < BEAM_N * L_N; e += 256) {
        fin_tok[sent * (BEAM_N * L_N) + e] = tmp_fin[e];
        tokens[sent * (BEAM_N * L_N) + e]  = tmp_tok[e];
    }
    for (int e = tid; e < BEAM_N * SLEN_N; e += 256)
        scores[sent * (BEAM_N * SLEN_N) + e] = tmp_sc[e];
    if (tid < 4) {
        fin_sc[sent * BEAM_N + tid] = nfin_s[tid];
        rmax_u[sent * BEAM_N + tid] = 0u;     // reset for next step's GEMM atomics
    }
}

// ---------------- final forced-EOS merge + output write ----------------
__global__ __launch_bounds__(256) void k_final(const float* __restrict__ logits,
                                               const unsigned* __restrict__ rmax_u,
                                               const float* __restrict__ halfsum,
                                               const int* __restrict__ tokens,
                                               const float* __restrict__ scores,
                                               const int* __restrict__ fin_tok,
                                               const float* __restrict__ fin_sc,
                                               float* __restrict__ out) {
    const int sent = blockIdx.x;
    const int tid = threadIdx.x;
    __shared__ int fsel_s[4]; __shared__ float nfin_s[4];
    if (tid == 0) {
        float allsc[8];
#pragma unroll
        for (int r = 0; r < 4; ++r) {
            const int row = sent * BEAM_N + r;
            const float rm = unsort_f32(rmax_u[row]);
            const float rl = (float)log((double)(halfsum[row * 2] + halfsum[row * 2 + 1]));
            const float lpE = ((logits[(size_t)row * NPAD + EOS_T] - rm) - rl);
            allsc[r] = fin_sc[sent * BEAM_N + r];
            allsc[4 + r] = (scores[row * SLEN_N + (MAXLEN_N - 1)] + lpE) / 65.0f;
        }
        bool used[8] = {false,false,false,false,false,false,false,false};
#pragma unroll
        for (int b = 0; b < 4; ++b) {
            int best = -1; float bvv = 0.f;
#pragma unroll
            for (int j = 0; j < 8; ++j) {
                if (used[j]) continue;
                if (best < 0 || allsc[j] > bvv) { best = j; bvv = allsc[j]; }
            }
            used[best] = true; fsel_s[b] = best; nfin_s[b] = bvv;
        }
    }
    __syncthreads();
    for (int e = tid; e < BEAM_N * L_N; e += 256) {
        const int b = e / L_N, p = e % L_N;
        const int s = fsel_s[b]; int valt;
        if (s < 4) {
            valt = fin_tok[(sent * BEAM_N + s) * L_N + p];
        } else {
            const int r = s - 4;
            valt = (p == MAXLEN_N + 1) ? EOS_T : tokens[(sent * BEAM_N + r) * L_N + p];
        }
        out[(size_t)(sent * BEAM_N + b) * L_N + p] = (float)valt;
    }
    if (tid < 4) out[BSZ_N * BEAM_N * L_N + sent * BEAM_N + tid] = nfin_s[tid];
}

extern "C" void kernel_launch(void* const* d_in, const int* in_sizes, int n_in,
                              void* d_out, int out_size, void* d_ws, size_t ws_size,
                              hipStream_t stream) {
    const float* emb = (const float*)d_in[0];
    const float* W   = (const float*)d_in[1];
    const float* pos = (const float*)d_in[2];
    float* out = (float*)d_out;

    char* w = (char*)d_ws;
    float*    logits  = (float*)w;    w += (size_t)BB * NPAD * 4;     // 25.76 MB
    unsigned* rmax_u  = (unsigned*)w; w += BB * 4;
    float*    halfsum = (float*)w;    w += BB * 2 * 4;
    u64*      htop    = (u64*)w;      w += (size_t)BB * 2 * 16 * 8;   // 32 KB
    int*      tokens  = (int*)w;      w += BB * L_N * 4;
    float*    scores  = (float*)w;    w += BB * SLEN_N * 4;
    int*      ftok    = (int*)w;      w += BB * L_N * 4;
    float*    fsc     = (float*)w;    w += BB * 4;

    k_init<<<32, 256, 0, stream>>>(tokens, scores, ftok, fsc, rmax_u);
    for (int s = 0; s < MAXLEN_N; ++s) {
        k_gemm<<<NPAD / 128, 512, 0, stream>>>(W, emb, pos, tokens, logits, rmax_u, s);
        k_scanexp<<<BB * 2, RT_THR, 0, stream>>>(logits, rmax_u, htop, halfsum);
        k_beam<<<BSZ_N, 256, 0, stream>>>(htop, rmax_u, halfsum, tokens, scores, ftok, fsc, s);
    }
    k_gemm<<<NPAD / 128, 512, 0, stream>>>(W, emb, pos, tokens, logits, rmax_u, MAXLEN_N);
    k_scanexp<<<BB * 2, RT_THR, 0, stream>>>(logits, rmax_u, htop, halfsum);
    k_final<<<BSZ_N, 256, 0, stream>>>(logits, rmax_u, halfsum, tokens, scores, ftok, fsc, out);
}

// Round 12
// 11808.086 us; speedup vs baseline: 1.9156x; 1.1816x over previous
//
#include <hip/hip_runtime.h>
#include <cstdint>
#include <cstddef>

#define VOCAB_N 50257
#define NPAD    50304          // padded row stride for logits (393 * 128)
#define DIM     1024
#define BSZ_N   32
#define BEAM_N  4
#define BB      128            // BSZ * BEAM
#define L_N     66             // MAXLEN + 2
#define SLEN_N  65             // MAXLEN + 1
#define MAXLEN_N 64
#define PAD_T   1
#define EOS_T   2
#define NEGV    (-1e9f)
#define SENTV   (-3.402823466e38f)
#define PW_BLOCK 128

typedef unsigned long long u64;
typedef __attribute__((ext_vector_type(8))) _Float16 f16x8;
typedef __attribute__((ext_vector_type(4))) _Float16 f16x4;
typedef __attribute__((ext_vector_type(4))) float f32x4;

// quarter decomposition of numpy's pairwise tree (root splits, exact):
// full: L=[0,25128), R=[25128,50257); L->q0[0,12560)+q1[12560,25128); R->q2[25128,37688)+q3[37688,50257)
__device__ __constant__ int QLO[4] = {0, 12560, 25128, 37688};
__device__ __constant__ int QHI[4] = {12560, 25128, 37688, 50257};

// ---------------- compile-time numpy pairwise_sum sub-trees ----------------
struct PWTree {
    int nleaf, nint, maxlev, root;
    int lstart[256], lnum[256], lslot[256];
    int eL[256], eR[256], eD[256];
    int lvl[32];
};

constexpr PWTree build_tree(int start, int n0) {
    PWTree t{};
    int fs[64] = {}, fn[64] = {}, fstt[64] = {}, fls[64] = {}, fll[64] = {};
    int tL[256] = {}, tR[256] = {}, tD[256] = {}, tLev[256] = {};
    int sp = 0, lc = 0, nc = 0, cnt = 0;
    fs[0] = start; fn[0] = n0; fstt[0] = 0; sp = 1;
    int retslot = -1, retlev = 0;
    while (sp > 0) {
        const int n = fn[sp - 1], s = fs[sp - 1], st = fstt[sp - 1];
        if (n <= PW_BLOCK) {
            t.lstart[lc] = s; t.lnum[lc] = n; t.lslot[lc] = cnt;
            retslot = cnt; retlev = 0; ++cnt; ++lc; --sp; continue;
        }
        int L = (n >> 1); L -= (L & 7);
        if (st == 0)      { fstt[sp - 1] = 1; fs[sp] = s;     fn[sp] = L;     fstt[sp] = 0; ++sp; }
        else if (st == 1) { fls[sp - 1] = retslot; fll[sp - 1] = retlev; fstt[sp - 1] = 2;
                            fs[sp] = s + L; fn[sp] = n - L; fstt[sp] = 0; ++sp; }
        else {
            const int lv = (fll[sp - 1] > retlev ? fll[sp - 1] : retlev) + 1;
            tL[nc] = fls[sp - 1]; tR[nc] = retslot; tD[nc] = cnt; tLev[nc] = lv;
            retslot = cnt; retlev = lv; ++cnt; ++nc; --sp;
        }
    }
    int maxlev = 0;
    for (int j = 0; j < nc; ++j) if (tLev[j] > maxlev) maxlev = tLev[j];
    int cl[40] = {};
    for (int j = 0; j < nc; ++j) cl[tLev[j]]++;
    int acc = 0;
    for (int v = 1; v <= maxlev; ++v) { t.lvl[v] = acc; acc += cl[v]; }
    t.lvl[maxlev + 1] = acc;
    int pos[40] = {};
    for (int v = 1; v <= maxlev; ++v) pos[v] = t.lvl[v];
    for (int j = 0; j < nc; ++j) {
        const int v = tLev[j]; const int p = pos[v]++;
        t.eL[p] = tL[j]; t.eR[p] = tR[j]; t.eD[p] = tD[j];
    }
    t.nleaf = lc; t.nint = nc; t.maxlev = maxlev; t.root = retslot;
    return t;
}

__device__ constexpr PWTree g_q0 = build_tree(0, 12560);
__device__ constexpr PWTree g_q1 = build_tree(12560, 12568);
__device__ constexpr PWTree g_q2 = build_tree(25128, 12560);
__device__ constexpr PWTree g_q3 = build_tree(37688, 12569);

// ---------------- sortable f32 encoding ----------------
__device__ __forceinline__ unsigned sortable_f32(float x) {
    unsigned u = __float_as_uint(x);
    return (u & 0x80000000u) ? ~u : (u | 0x80000000u);
}
__device__ __forceinline__ float unsort_f32(unsigned s) {
    unsigned u = (s & 0x80000000u) ? (s & 0x7fffffffu) : ~s;
    return __uint_as_float(u);
}

// ---------------- init state ----------------
__global__ void k_init(int* __restrict__ tokens, float* __restrict__ scores,
                       int* __restrict__ fin_tok, float* __restrict__ fin_sc,
                       unsigned* __restrict__ rmax_u) {
    int i = blockIdx.x * blockDim.x + threadIdx.x;
    int st = gridDim.x * blockDim.x;
    for (int k = i; k < BB * L_N; k += st) tokens[k] = ((k % L_N) == 0) ? EOS_T : PAD_T;
    for (int k = i; k < BB * SLEN_N; k += st) scores[k] = 0.f;
    for (int k = i; k < BB * L_N; k += st) fin_tok[k] = 0;
    for (int k = i; k < BB; k += st) { fin_sc[k] = NEGV; rmax_u[k] = 0u; }
}

// ---------------- exact scaled 2-way f16 split: x*4096 == h0 + h1 + O(2^-24 x) ----------------
__device__ __forceinline__ void split2(float x, _Float16& h0, _Float16& h1) {
    const float xs = x * 4096.f;       // exact (power of 2)
    h0 = (_Float16)xs;                 // RN
    const float r = xs - (float)h0;    // exact
    h1 = (_Float16)r;                  // RN
}

// ---------------- once per call: pre-split W into f16 planes, transposed [col][k] ----------------
__global__ __launch_bounds__(256) void k_wsplit(const float* __restrict__ W,
                                                _Float16* __restrict__ Wsp) {
    __shared__ __align__(16) _Float16 B[2][64][40];
    const int bid = blockIdx.x;
    const int ct = bid % 786, kt = bid / 786;
    const int n0 = ct * 64, k0 = kt * 32;
    const int tid = threadIdx.x;
    const int c = tid & 63, kk = tid >> 6;     // kk 0..3, 8 k each
#pragma unroll
    for (int j = 0; j < 8; ++j) {
        const int k = kk * 8 + j;
        float wv = 0.f;
        if (n0 + c < VOCAB_N) wv = W[(size_t)(k0 + k) * VOCAB_N + n0 + c];
        _Float16 b0, b1;
        split2(wv, b0, b1);
        B[0][c][k] = b0; B[1][c][k] = b1;
    }
    __syncthreads();
    const int g = tid & 3, cc = (tid >> 2) & 63;
#pragma unroll
    for (int p = 0; p < 2; ++p)
        *(f16x8*)&Wsp[((size_t)p * NPAD + n0 + cc) * 1024 + k0 + g * 8] =
            *(const f16x8*)&B[p][cc][g * 8];
}

// ---------------- per step: pre-split H (emb+pos, single-rounded) ----------------
__global__ __launch_bounds__(256) void k_hsplit(const float* __restrict__ emb,
                                                const float* __restrict__ pos_emb,
                                                const int* __restrict__ tokens,
                                                _Float16* __restrict__ Hsp, int step) {
    const int row = blockIdx.x;           // 128
    const int tid = threadIdx.x;          // 256 -> 4 elems each
    const int tok = tokens[row * L_N + step];
    const float4 e = *(const float4*)(emb + (size_t)tok * DIM + tid * 4);
    const float4 p = *(const float4*)(pos_emb + (size_t)step * DIM + tid * 4);
    const float hv[4] = {e.x + p.x, e.y + p.y, e.z + p.z, e.w + p.w};
    f16x4 o0, o1;
#pragma unroll
    for (int d = 0; d < 4; ++d) {
        _Float16 a0, a1;
        split2(hv[d], a0, a1);
        o0[d] = a0; o1[d] = a1;
    }
    *(f16x4*)&Hsp[(size_t)0 * 131072 + row * 1024 + tid * 4] = o0;
    *(f16x4*)&Hsp[(size_t)1 * 131072 + row * 1024 + tid * 4] = o1;
}

// ---------------- fast MFMA GEMM: pure-copy staging + reg prefetch ----------------
__global__ __launch_bounds__(512) void k_gemm_fast(const _Float16* __restrict__ Wsp,
                                                   const _Float16* __restrict__ Hsp,
                                                   float* __restrict__ logits,
                                                   unsigned* __restrict__ rmax_u) {
    __shared__ __align__(16) _Float16 Ha[2][128][40];   // 20 KB
    __shared__ __align__(16) _Float16 Wb[2][128][40];   // 20 KB
    __shared__ unsigned smax[128];
    const int tid = threadIdx.x;
    const int n0 = blockIdx.x * 128;
    const int lane = tid & 63, wid = tid >> 6;
    const int la = lane & 15, g = lane >> 4;
    const int wr = wid >> 1, wc = wid & 1;              // wave: rows wr*32, cols wc*64
    const int sg = tid & 3, sidx = (tid >> 2) & 127;    // staging coords

    if (tid < 128) smax[tid] = 0u;

    f32x4 acc[2][4];
#pragma unroll
    for (int mf = 0; mf < 2; ++mf)
#pragma unroll
        for (int nf = 0; nf < 4; ++nf)
#pragma unroll
            for (int j = 0; j < 4; ++j) acc[mf][nf][j] = 0.f;

    const _Float16* H0 = Hsp;
    const _Float16* H1 = Hsp + 131072;
    const _Float16* W0 = Wsp;
    const _Float16* W1 = Wsp + (size_t)NPAD * 1024;
    const size_t hoff = (size_t)sidx * 1024 + sg * 8;
    const size_t woff = (size_t)(n0 + sidx) * 1024 + sg * 8;

    f16x8 rH0 = *(const f16x8*)&H0[hoff];
    f16x8 rH1 = *(const f16x8*)&H1[hoff];
    f16x8 rW0 = *(const f16x8*)&W0[woff];
    f16x8 rW1 = *(const f16x8*)&W1[woff];

    for (int t = 0; t < 32; ++t) {
        *(f16x8*)&Ha[0][sidx][sg * 8] = rH0;
        *(f16x8*)&Ha[1][sidx][sg * 8] = rH1;
        *(f16x8*)&Wb[0][sidx][sg * 8] = rW0;
        *(f16x8*)&Wb[1][sidx][sg * 8] = rW1;
        __syncthreads();
        if (t + 1 < 32) {
            const int k0 = (t + 1) * 32;
            rH0 = *(const f16x8*)&H0[hoff + k0];
            rH1 = *(const f16x8*)&H1[hoff + k0];
            rW0 = *(const f16x8*)&W0[woff + k0];
            rW1 = *(const f16x8*)&W1[woff + k0];
        }
        f16x8 a[2][2];
#pragma unroll
        for (int mf = 0; mf < 2; ++mf) {
            a[mf][0] = *(const f16x8*)&Ha[0][wr * 32 + mf * 16 + la][g * 8];
            a[mf][1] = *(const f16x8*)&Ha[1][wr * 32 + mf * 16 + la][g * 8];
        }
#pragma unroll
        for (int nf = 0; nf < 4; ++nf) {
            const int c = wc * 64 + nf * 16 + la;
            const f16x8 b0 = *(const f16x8*)&Wb[0][c][g * 8];
            const f16x8 b1 = *(const f16x8*)&Wb[1][c][g * 8];
#pragma unroll
            for (int mf = 0; mf < 2; ++mf) {
                f32x4 cc = acc[mf][nf];
                cc = __builtin_amdgcn_mfma_f32_16x16x32_f16(a[mf][0], b0, cc, 0, 0, 0);
                cc = __builtin_amdgcn_mfma_f32_16x16x32_f16(a[mf][0], b1, cc, 0, 0, 0);
                cc = __builtin_amdgcn_mfma_f32_16x16x32_f16(a[mf][1], b0, cc, 0, 0, 0);
                acc[mf][nf] = cc;
            }
        }
        __syncthreads();
    }

    // epilogue: unscale (exact 2^-24), store, row-max atomics
#pragma unroll
    for (int mf = 0; mf < 2; ++mf) {
        const int row = wr * 32 + mf * 16 + g * 4;
        float rmx[4] = {SENTV, SENTV, SENTV, SENTV};
#pragma unroll
        for (int nf = 0; nf < 4; ++nf) {
            const int col = n0 + wc * 64 + nf * 16 + la;
#pragma unroll
            for (int j = 0; j < 4; ++j) {
                const float v = acc[mf][nf][j] * 0x1p-24f;
                logits[(size_t)(row + j) * NPAD + col] = v;
                rmx[j] = fmaxf(rmx[j], v);
            }
        }
#pragma unroll
        for (int j = 0; j < 4; ++j) {
            float v = rmx[j];
            v = fmaxf(v, __shfl_xor(v, 1, 64));
            v = fmaxf(v, __shfl_xor(v, 2, 64));
            v = fmaxf(v, __shfl_xor(v, 4, 64));
            v = fmaxf(v, __shfl_xor(v, 8, 64));
            if (la == 0) atomicMax(&smax[row + j], sortable_f32(v));
        }
    }
    __syncthreads();
    if (tid < 128) atomicMax(&rmax_u[tid], smax[tid]);
}

// ---------------- slow-path GEMM (r11-proven, in-kernel split) ----------------
#define KT 32
__global__ __launch_bounds__(512) void k_gemm_slow(const float* __restrict__ W,
                                                   const float* __restrict__ emb,
                                                   const float* __restrict__ pos_emb,
                                                   const int* __restrict__ tokens,
                                                   float* __restrict__ logits,
                                                   unsigned* __restrict__ rmax_u, int step) {
    __shared__ __align__(16) _Float16 Ha[2][128][40];
    __shared__ __align__(16) _Float16 Wb[2][128][40];
    __shared__ unsigned smax[128];
    const int tid = threadIdx.x;
    const int n0 = blockIdx.x * 128;
    const bool full = (n0 + 128 <= VOCAB_N);
    const int lane = tid & 63, wid = tid >> 6;
    const int wr = wid >> 1, wc = wid & 1;
    const int la = lane & 15, g = lane >> 4;
    const int hrow = tid & 127, hkq = tid >> 7;
    const int tokH = tokens[hrow * L_N + step];
    const float* eprow = emb + (size_t)tokH * DIM;
    const float* pprow = pos_emb + (size_t)step * DIM;
    const int wcq = tid & 31, wk = tid >> 5;

    if (tid < 128) smax[tid] = 0u;

    f32x4 acc[2][4];
#pragma unroll
    for (int mf = 0; mf < 2; ++mf)
#pragma unroll
        for (int nf = 0; nf < 4; ++nf)
#pragma unroll
            for (int j = 0; j < 4; ++j) acc[mf][nf][j] = 0.f;

    for (int k0 = 0; k0 < DIM; k0 += KT) {
#pragma unroll
        for (int d = 0; d < 4; ++d) {
            const int c = wcq + 32 * d;
#pragma unroll
            for (int qq = 0; qq < 2; ++qq) {
                const int kk = wk + 16 * qq;
                float wv = 0.f;
                if (full || (n0 + c < VOCAB_N))
                    wv = W[(size_t)(k0 + kk) * VOCAB_N + n0 + c];
                _Float16 b0, b1;
                split2(wv, b0, b1);
                Wb[0][c][kk] = b0;
                Wb[1][c][kk] = b1;
            }
        }
#pragma unroll
        for (int qq = 0; qq < 2; ++qq) {
            const int kq = hkq + 4 * qq;
            const float4 e0 = *(const float4*)(eprow + k0 + kq * 4);
            const float4 p0 = *(const float4*)(pprow + k0 + kq * 4);
            const float hv[4] = {e0.x + p0.x, e0.y + p0.y, e0.z + p0.z, e0.w + p0.w};
            f16x4 o0, o1;
#pragma unroll
            for (int d = 0; d < 4; ++d) {
                _Float16 a0, a1;
                split2(hv[d], a0, a1);
                o0[d] = a0; o1[d] = a1;
            }
            *(f16x4*)&Ha[0][hrow][kq * 4] = o0;
            *(f16x4*)&Ha[1][hrow][kq * 4] = o1;
        }
        __syncthreads();
        f16x8 af[2][2];
#pragma unroll
        for (int mf = 0; mf < 2; ++mf)
#pragma unroll
            for (int p = 0; p < 2; ++p)
                af[mf][p] = *(const f16x8*)&Ha[p][wr * 32 + mf * 16 + la][g * 8];
#pragma unroll
        for (int nf = 0; nf < 4; ++nf) {
            const int c = wc * 64 + nf * 16 + la;
            const f16x8 b0 = *(const f16x8*)&Wb[0][c][g * 8];
            const f16x8 b1 = *(const f16x8*)&Wb[1][c][g * 8];
#pragma unroll
            for (int mf = 0; mf < 2; ++mf) {
                f32x4 cc = acc[mf][nf];
                cc = __builtin_amdgcn_mfma_f32_16x16x32_f16(af[mf][0], b0, cc, 0, 0, 0);
                cc = __builtin_amdgcn_mfma_f32_16x16x32_f16(af[mf][0], b1, cc, 0, 0, 0);
                cc = __builtin_amdgcn_mfma_f32_16x16x32_f16(af[mf][1], b0, cc, 0, 0, 0);
                acc[mf][nf] = cc;
            }
        }
        __syncthreads();
    }
#pragma unroll
    for (int mf = 0; mf < 2; ++mf) {
        const int row = wr * 32 + mf * 16 + g * 4;
        float rmx[4] = {SENTV, SENTV, SENTV, SENTV};
#pragma unroll
        for (int nf = 0; nf < 4; ++nf) {
            const int col = n0 + wc * 64 + nf * 16 + la;
#pragma unroll
            for (int j = 0; j < 4; ++j) {
                const float v = acc[mf][nf][j] * 0x1p-24f;
                logits[(size_t)(row + j) * NPAD + col] = v;
                rmx[j] = fmaxf(rmx[j], v);
            }
        }
#pragma unroll
        for (int j = 0; j < 4; ++j) {
            float v = rmx[j];
            v = fmaxf(v, __shfl_xor(v, 1, 64));
            v = fmaxf(v, __shfl_xor(v, 2, 64));
            v = fmaxf(v, __shfl_xor(v, 4, 64));
            v = fmaxf(v, __shfl_xor(v, 8, 64));
            if (la == 0) atomicMax(&smax[row + j], sortable_f32(v));
        }
    }
    __syncthreads();
    if (tid < 128) atomicMax(&rmax_u[tid], smax[tid]);
}

// ---------------- packed (x, idx) keys ----------------
__device__ __forceinline__ u64 pack_key(float x, int tk) {
    return ((u64)sortable_f32(x) << 32) | (unsigned)(VOCAB_N - tk);
}
__device__ __forceinline__ void insk16(u64 k, u64 lst[16]) {
#pragma unroll
    for (int p = 0; p < 16; ++p) {
        if (k > lst[p]) { u64 o = lst[p]; lst[p] = k; k = o; }
    }
}
__device__ __forceinline__ u64 wave_max_u64(u64 v) {
#pragma unroll
    for (int o = 32; o > 0; o >>= 1) {
        u64 w = __shfl_xor(v, o, 64);
        if (w > v) v = w;
    }
    return v;
}

// ---------------- fused per-quarter: top-16 (excl PAD) + numpy-exact pairwise exp-sum ----------------
#define RT2 256
__global__ __launch_bounds__(RT2) void k_scanexp(const float* __restrict__ logits,
                                                 const unsigned* __restrict__ rmax_u,
                                                 u64* __restrict__ htop,
                                                 float* __restrict__ qsum) {
    const int hb = blockIdx.x;            // 0..511
    const int row = hb >> 2, q = hb & 3;
    const int tid = threadIdx.x;
    const int lane = tid & 63, wid = tid >> 6;   // 4 waves
    const float* x = logits + (size_t)row * NPAD;
    const int lo = QLO[q], hi = QHI[q];
    const float mrow = unsort_f32(rmax_u[row]);

    u64 lst[16];
#pragma unroll
    for (int p = 0; p < 16; ++p) lst[p] = 0ULL;
    for (int v = lo + tid * 4; v + 3 < hi; v += RT2 * 4) {
        const float4 t = *(const float4*)(x + v);
        const float va[4] = {t.x, t.y, t.z, t.w};
#pragma unroll
        for (int u = 0; u < 4; ++u) {
            const int tk = v + u;
            if (tk == PAD_T) continue;
            const u64 key = pack_key(va[u], tk);
            if (key > lst[15]) insk16(key, lst);
        }
    }
    if (q == 3 && tid == 0) {             // tail element 50256
        const int tk = VOCAB_N - 1;
        const u64 key = pack_key(x[tk], tk);
        if (key > lst[15]) insk16(key, lst);
    }

    // per-wave top-16 tournament
    __shared__ u64 wtop[4][16];
    for (int pass = 0; pass < 16; ++pass) {
        const u64 cand = lst[0];
        const u64 mx = wave_max_u64(cand);
        const u64 ball = __ballot(cand == mx);
        const int first = __ffsll((u64)ball) - 1;
        if (lane == first) {
#pragma unroll
            for (int p = 0; p < 15; ++p) lst[p] = lst[p + 1];
            lst[15] = 0ULL;
        }
        if (lane == 0) wtop[wid][pass] = mx;
    }
    __syncthreads();

    // wave 0 merges 4x16 = 64 keys -> top-16
    __shared__ u64 sfin[16];
    if (tid < 64) {
        const u64 mine = wtop[tid >> 4][tid & 15];
        bool taken = false;
        for (int pass = 0; pass < 16; ++pass) {
            const u64 cand = taken ? 0ULL : mine;
            const u64 mx = wave_max_u64(cand);
            const u64 ball = __ballot(cand == mx);
            const int first = __ffsll((u64)ball) - 1;
            if (tid == first) taken = true;
            if (tid == 0) sfin[pass] = mx;
        }
    }

    // numpy pairwise exp-sum over quarter sub-tree (bit-exact proven structure)
    const PWTree& T = (q == 0) ? g_q0 : (q == 1) ? g_q1 : (q == 2) ? g_q2 : g_q3;
    __shared__ float slot[512];
    for (int leaf = tid; leaf < T.nleaf; leaf += RT2) {
        const int s = T.lstart[leaf];
        const int n = T.lnum[leaf];
        float res;
        if (n < 8) {
            res = 0.f;
            for (int i = 0; i < n; ++i) res += expf(x[s + i] - mrow);
        } else {
            float r0 = expf(x[s + 0] - mrow), r1 = expf(x[s + 1] - mrow);
            float r2 = expf(x[s + 2] - mrow), r3 = expf(x[s + 3] - mrow);
            float r4 = expf(x[s + 4] - mrow), r5 = expf(x[s + 5] - mrow);
            float r6 = expf(x[s + 6] - mrow), r7 = expf(x[s + 7] - mrow);
            int i = 8;
            const int lim = n - (n & 7);
            for (; i < lim; i += 8) {
                r0 += expf(x[s + i + 0] - mrow); r1 += expf(x[s + i + 1] - mrow);
                r2 += expf(x[s + i + 2] - mrow); r3 += expf(x[s + i + 3] - mrow);
                r4 += expf(x[s + i + 4] - mrow); r5 += expf(x[s + i + 5] - mrow);
                r6 += expf(x[s + i + 6] - mrow); r7 += expf(x[s + i + 7] - mrow);
            }
            res = ((r0 + r1) + (r2 + r3)) + ((r4 + r5) + (r6 + r7));
            for (; i < n; ++i) res += expf(x[s + i] - mrow);
        }
        slot[T.lslot[leaf]] = res;
    }
    __syncthreads();
    for (int lev = 1; lev <= T.maxlev; ++lev) {
        for (int j = T.lvl[lev] + tid; j < T.lvl[lev + 1]; j += RT2)
            slot[T.eD[j]] = slot[T.eL[j]] + slot[T.eR[j]];
        __syncthreads();
    }
    if (tid == 0) qsum[hb] = slot[T.root];
    if (tid < 16) htop[hb * 16 + tid] = sfin[tid];
}

// ---------------- per-sentence: merge quarters + top-8 + literal bookkeeping ----------------
__global__ __launch_bounds__(256) void k_beam(const u64* __restrict__ htop,
                                              unsigned* __restrict__ rmax_u,
                                              const float* __restrict__ qsum,
                                              int* __restrict__ tokens,
                                              float* __restrict__ scores,
                                              int* __restrict__ fin_tok,
                                              float* __restrict__ fin_sc,
                                              int step) {
    const int sent = blockIdx.x;
    const int tid = threadIdx.x;
    const int rN = (step == 0) ? 1 : BEAM_N;

    __shared__ u64 keys[4][64];
    for (int e = tid; e < 256; e += 256) {
        const int r = e >> 6, i = e & 63;
        keys[r][i] = htop[((sent * BEAM_N + r) * 4 + (i >> 4)) * 16 + (i & 15)];
    }
    __syncthreads();

    // 4-way merge of desc-sorted 16-lists -> row top-16 (keys strictly distinct)
    __shared__ u64 merged[4][16];
    if (tid < 4) {
        int ia[4] = {0, 0, 0, 0};
        for (int o = 0; o < 16; ++o) {
            u64 best = 0ULL; int bq = 0;
#pragma unroll
            for (int qq = 0; qq < 4; ++qq) {
                const u64 h = (ia[qq] < 16) ? keys[tid][qq * 16 + ia[qq]] : 0ULL;
                if (h > best) { best = h; bq = qq; }
            }
            merged[tid][o] = best; ia[bq]++;
        }
    }
    __syncthreads();

    __shared__ float bval[64]; __shared__ int bflat[64];
    if (tid < 16 * rN) {
        const int r = tid >> 4, j = tid & 15;
        const int row = sent * BEAM_N + r;
        const float rm = unsort_f32(rmax_u[row]);
        const float rl = (float)log((double)((qsum[row * 4] + qsum[row * 4 + 1]) +
                                             (qsum[row * 4 + 2] + qsum[row * 4 + 3])));
        const float prev = (step == 0) ? 0.f : scores[row * SLEN_N + step - 1];
        const u64 k = merged[r][j];
        const float xv = unsort_f32((unsigned)(k >> 32));
        const int   tk = VOCAB_N - (int)(k & 0xFFFFFFFFu);
        bval[tid]  = ((xv - rm) - rl) + prev;   // exact ref association
        bflat[tid] = r * VOCAB_N + tk;
    }
    __syncthreads();
    __shared__ float cand_sc[8]; __shared__ int cand_flat[8];
    if (tid == 0) {
        const int nC = 16 * rN;
        for (int pass = 0; pass < 8; ++pass) {
            float bv = SENTV; int bi = 0x7fffffff; int bs = -1;
            for (int k = 0; k < nC; ++k) {
                const float v = bval[k]; const int ix = bflat[k];
                if (v > bv || (v == bv && ix < bi)) { bv = v; bi = ix; bs = k; }
            }
            cand_sc[pass] = bv; cand_flat[pass] = bi;
            bval[bs] = SENTV; bflat[bs] = 0x7fffffff;
        }
    }
    __syncthreads();

    __shared__ int   cur_tok[BEAM_N * L_N];
    __shared__ int   cur_fin[BEAM_N * L_N];
    __shared__ float cur_sc[BEAM_N * SLEN_N];
    for (int e = tid; e < BEAM_N * L_N; e += 256) {
        cur_tok[e] = tokens[sent * (BEAM_N * L_N) + e];
        cur_fin[e] = fin_tok[sent * (BEAM_N * L_N) + e];
    }
    for (int e = tid; e < BEAM_N * SLEN_N; e += 256)
        cur_sc[e] = scores[sent * (BEAM_N * SLEN_N) + e];
    __syncthreads();

    __shared__ int   tmp_fin[BEAM_N * L_N];
    __shared__ int   tmp_tok[BEAM_N * L_N];
    __shared__ float tmp_sc[BEAM_N * SLEN_N];
    __shared__ float nfin_s[BEAM_N];
    if (tid == 0) {
        int cb[8], ct[8];
#pragma unroll
        for (int j = 0; j < 8; ++j) {
            cb[j] = cand_flat[j] / VOCAB_N;
            ct[j] = cand_flat[j] % VOCAB_N;
        }
        float allsc[8];
#pragma unroll
        for (int j = 0; j < 4; ++j) allsc[j] = fin_sc[sent * BEAM_N + j];
#pragma unroll
        for (int j = 0; j < 4; ++j)
            allsc[4 + j] = (ct[j] == EOS_T) ? (cand_sc[j] / (float)(step + 1)) : NEGV;
        int fsel[4]; float nfin[4];
        bool used[8] = {false,false,false,false,false,false,false,false};
#pragma unroll
        for (int b = 0; b < 4; ++b) {
            int best = -1; float bvv = 0.f;
#pragma unroll
            for (int j = 0; j < 8; ++j) {
                if (used[j]) continue;
                if (best < 0 || allsc[j] > bvv) { best = j; bvv = allsc[j]; }
            }
            used[best] = true; fsel[b] = best; nfin[b] = bvv;
        }
#pragma unroll
        for (int b = 0; b < 4; ++b) {
            const int s = fsel[b];
            if (s < 4) {
                for (int p = 0; p < L_N; ++p) tmp_fin[b * L_N + p] = cur_fin[s * L_N + p];
            } else {
                const int bm = cb[s - 4];
                for (int p = 0; p < L_N; ++p)
                    tmp_fin[b * L_N + p] = (p == step + 1) ? EOS_T : cur_tok[bm * L_N + p];
            }
        }
        int ab[4], atk[4]; float asc[4]; int na = 0;
#pragma unroll
        for (int j = 0; j < 8; ++j) {
            if (na < 4 && ct[j] != EOS_T) { ab[na] = cb[j]; atk[na] = ct[j]; asc[na] = cand_sc[j]; ++na; }
        }
#pragma unroll
        for (int b = 0; b < 4; ++b) {
            const int bm = ab[b];
            for (int p = 0; p < L_N; ++p)
                tmp_tok[b * L_N + p] = (p == step + 1) ? atk[b] : cur_tok[bm * L_N + p];
            for (int p = 0; p < SLEN_N; ++p)
                tmp_sc[b * SLEN_N + p] = (p == step) ? asc[b] : cur_sc[bm * SLEN_N + p];
        }
#pragma unroll
        for (int b = 0; b < 4; ++b) nfin_s[b] = nfin[b];
    }
    __syncthreads();

    for (int e = tid; e < BEAM_N * L_N; e += 256) {
        fin_tok[sent * (BEAM_N * L_N) + e] = tmp_fin[e];
        tokens[sent * (BEAM_N * L_N) + e]  = tmp_tok[e];
    }
    for (int e = tid; e < BEAM_N * SLEN_N; e += 256)
        scores[sent * (BEAM_N * SLEN_N) + e] = tmp_sc[e];
    if (tid < 4) {
        fin_sc[sent * BEAM_N + tid] = nfin_s[tid];
        rmax_u[sent * BEAM_N + tid] = 0u;     // reset for next step
    }
}

// ---------------- final forced-EOS merge + output write ----------------
__global__ __launch_bounds__(256) void k_final(const float* __restrict__ logits,
                                               const unsigned* __restrict__ rmax_u,
                                               const float* __restrict__ qsum,
                                               const int* __restrict__ tokens,
                                               const float* __restrict__ scores,
                                               const int* __restrict__ fin_tok,
                                               const float* __restrict__ fin_sc,
                                               float* __restrict__ out) {
    const int sent = blockIdx.x;
    const int tid = threadIdx.x;
    __shared__ int fsel_s[4]; __shared__ float nfin_s[4];
    if (tid == 0) {
        float allsc[8];
#pragma unroll
        for (int r = 0; r < 4; ++r) {
            const int row = sent * BEAM_N + r;
            const float rm = unsort_f32(rmax_u[row]);
            const float rl = (float)log((double)((qsum[row * 4] + qsum[row * 4 + 1]) +
                                                 (qsum[row * 4 + 2] + qsum[row * 4 + 3])));
            const float lpE = ((logits[(size_t)row * NPAD + EOS_T] - rm) - rl);
            allsc[r] = fin_sc[sent * BEAM_N + r];
            allsc[4 + r] = (scores[row * SLEN_N + (MAXLEN_N - 1)] + lpE) / 65.0f;
        }
        bool used[8] = {false,false,false,false,false,false,false,false};
#pragma unroll
        for (int b = 0; b < 4; ++b) {
            int best = -1; float bvv = 0.f;
#pragma unroll
            for (int j = 0; j < 8; ++j) {
                if (used[j]) continue;
                if (best < 0 || allsc[j] > bvv) { best = j; bvv = allsc[j]; }
            }
            used[best] = true; fsel_s[b] = best; nfin_s[b] = bvv;
        }
    }
    __syncthreads();
    for (int e = tid; e < BEAM_N * L_N; e += 256) {
        const int b = e / L_N, p = e % L_N;
        const int s = fsel_s[b]; int valt;
        if (s < 4) {
            valt = fin_tok[(sent * BEAM_N + s) * L_N + p];
        } else {
            const int r = s - 4;
            valt = (p == MAXLEN_N + 1) ? EOS_T : tokens[(sent * BEAM_N + r) * L_N + p];
        }
        out[(size_t)(sent * BEAM_N + b) * L_N + p] = (float)valt;
    }
    if (tid < 4) out[BSZ_N * BEAM_N * L_N + sent * BEAM_N + tid] = nfin_s[tid];
}

extern "C" void kernel_launch(void* const* d_in, const int* in_sizes, int n_in,
                              void* d_out, int out_size, void* d_ws, size_t ws_size,
                              hipStream_t stream) {
    const float* emb = (const float*)d_in[0];
    const float* W   = (const float*)d_in[1];
    const float* pos = (const float*)d_in[2];
    float* out = (float*)d_out;

    char* w = (char*)d_ws;
    size_t off = 0;
    auto alloc = [&](size_t bytes) { void* p = w + off; off += (bytes + 15) & ~(size_t)15; return p; };
    float*    logits = (float*)alloc((size_t)BB * NPAD * 4);
    unsigned* rmax_u = (unsigned*)alloc(BB * 4);
    float*    qsum   = (float*)alloc(BB * 4 * 4);
    u64*      htop   = (u64*)alloc((size_t)BB * 4 * 16 * 8);
    int*      tokens = (int*)alloc(BB * L_N * 4);
    float*    scores = (float*)alloc(BB * SLEN_N * 4);
    int*      ftok   = (int*)alloc(BB * L_N * 4);
    float*    fsc    = (float*)alloc(BB * 4);
    _Float16* Wsp    = (_Float16*)alloc((size_t)2 * NPAD * 1024 * 2);
    _Float16* Hsp    = (_Float16*)alloc((size_t)2 * 128 * 1024 * 2);
    const bool fast = (off <= ws_size);

    k_init<<<32, 256, 0, stream>>>(tokens, scores, ftok, fsc, rmax_u);
    if (fast) k_wsplit<<<786 * 32, 256, 0, stream>>>(W, Wsp);
    for (int s = 0; s < MAXLEN_N; ++s) {
        if (fast) {
            k_hsplit<<<128, 256, 0, stream>>>(emb, pos, tokens, Hsp, s);
            k_gemm_fast<<<NPAD / 128, 512, 0, stream>>>(Wsp, Hsp, logits, rmax_u);
        } else {
            k_gemm_slow<<<NPAD / 128, 512, 0, stream>>>(W, emb, pos, tokens, logits, rmax_u, s);
        }
        k_scanexp<<<BB * 4, RT2, 0, stream>>>(logits, rmax_u, htop, qsum);
        k_beam<<<BSZ_N, 256, 0, stream>>>(htop, rmax_u, qsum, tokens, scores, ftok, fsc, s);
    }
    if (fast) {
        k_hsplit<<<128, 256, 0, stream>>>(emb, pos, tokens, Hsp, MAXLEN_N);
        k_gemm_fast<<<NPAD / 128, 512, 0, stream>>>(Wsp, Hsp, logits, rmax_u);
    } else {
        k_gemm_slow<<<NPAD / 128, 512, 0, stream>>>(W, emb, pos, tokens, logits, rmax_u, MAXLEN_N);
    }
    k_scanexp<<<BB * 4, RT2, 0, stream>>>(logits, rmax_u, htop, qsum);
    k_final<<<BSZ_N, 256, 0, stream>>>(logits, rmax_u, qsum, tokens, scores, ftok, fsc, out);
}

// Round 13
// 11354.454 us; speedup vs baseline: 1.9921x; 1.0400x over previous
//
#include <hip/hip_runtime.h>
#include <cstdint>
#include <cstddef>

#define VOCAB_N 50257
#define NPAD    50304          // padded row stride for logits (393 * 128)
#define DIM     1024
#define BSZ_N   32
#define BEAM_N  4
#define BB      128            // BSZ * BEAM
#define L_N     66             // MAXLEN + 2
#define SLEN_N  65             // MAXLEN + 1
#define MAXLEN_N 64
#define PAD_T   1
#define EOS_T   2
#define NEGV    (-1e9f)
#define SENTV   (-3.402823466e38f)
#define PW_BLOCK 128

typedef unsigned long long u64;
typedef __attribute__((ext_vector_type(8))) _Float16 f16x8;
typedef __attribute__((ext_vector_type(4))) _Float16 f16x4;
typedef __attribute__((ext_vector_type(4))) float f32x4;

// quarter decomposition of numpy's pairwise tree (root splits, exact)
__device__ __constant__ int QLO[4] = {0, 12560, 25128, 37688};
__device__ __constant__ int QHI[4] = {12560, 25128, 37688, 50257};

// ---------------- compile-time numpy pairwise_sum sub-trees ----------------
struct PWTree {
    int nleaf, nint, maxlev, root;
    int lstart[256], lnum[256], lslot[256];
    int eL[256], eR[256], eD[256];
    int lvl[32];
};

constexpr PWTree build_tree(int start, int n0) {
    PWTree t{};
    int fs[64] = {}, fn[64] = {}, fstt[64] = {}, fls[64] = {}, fll[64] = {};
    int tL[256] = {}, tR[256] = {}, tD[256] = {}, tLev[256] = {};
    int sp = 0, lc = 0, nc = 0, cnt = 0;
    fs[0] = start; fn[0] = n0; fstt[0] = 0; sp = 1;
    int retslot = -1, retlev = 0;
    while (sp > 0) {
        const int n = fn[sp - 1], s = fs[sp - 1], st = fstt[sp - 1];
        if (n <= PW_BLOCK) {
            t.lstart[lc] = s; t.lnum[lc] = n; t.lslot[lc] = cnt;
            retslot = cnt; retlev = 0; ++cnt; ++lc; --sp; continue;
        }
        int L = (n >> 1); L -= (L & 7);
        if (st == 0)      { fstt[sp - 1] = 1; fs[sp] = s;     fn[sp] = L;     fstt[sp] = 0; ++sp; }
        else if (st == 1) { fls[sp - 1] = retslot; fll[sp - 1] = retlev; fstt[sp - 1] = 2;
                            fs[sp] = s + L; fn[sp] = n - L; fstt[sp] = 0; ++sp; }
        else {
            const int lv = (fll[sp - 1] > retlev ? fll[sp - 1] : retlev) + 1;
            tL[nc] = fls[sp - 1]; tR[nc] = retslot; tD[nc] = cnt; tLev[nc] = lv;
            retslot = cnt; retlev = lv; ++cnt; ++nc; --sp;
        }
    }
    int maxlev = 0;
    for (int j = 0; j < nc; ++j) if (tLev[j] > maxlev) maxlev = tLev[j];
    int cl[40] = {};
    for (int j = 0; j < nc; ++j) cl[tLev[j]]++;
    int acc = 0;
    for (int v = 1; v <= maxlev; ++v) { t.lvl[v] = acc; acc += cl[v]; }
    t.lvl[maxlev + 1] = acc;
    int pos[40] = {};
    for (int v = 1; v <= maxlev; ++v) pos[v] = t.lvl[v];
    for (int j = 0; j < nc; ++j) {
        const int v = tLev[j]; const int p = pos[v]++;
        t.eL[p] = tL[j]; t.eR[p] = tR[j]; t.eD[p] = tD[j];
    }
    t.nleaf = lc; t.nint = nc; t.maxlev = maxlev; t.root = retslot;
    return t;
}

__device__ constexpr PWTree g_q0 = build_tree(0, 12560);
__device__ constexpr PWTree g_q1 = build_tree(12560, 12568);
__device__ constexpr PWTree g_q2 = build_tree(25128, 12560);
__device__ constexpr PWTree g_q3 = build_tree(37688, 12569);

// ---------------- sortable f32 encoding ----------------
__device__ __forceinline__ unsigned sortable_f32(float x) {
    unsigned u = __float_as_uint(x);
    return (u & 0x80000000u) ? ~u : (u | 0x80000000u);
}
__device__ __forceinline__ float unsort_f32(unsigned s) {
    unsigned u = (s & 0x80000000u) ? (s & 0x7fffffffu) : ~s;
    return __uint_as_float(u);
}

// ---------------- init state ----------------
__global__ void k_init(int* __restrict__ tokens, float* __restrict__ scores,
                       int* __restrict__ fin_tok, float* __restrict__ fin_sc,
                       unsigned* __restrict__ rmax_u) {
    int i = blockIdx.x * blockDim.x + threadIdx.x;
    int st = gridDim.x * blockDim.x;
    for (int k = i; k < BB * L_N; k += st) tokens[k] = ((k % L_N) == 0) ? EOS_T : PAD_T;
    for (int k = i; k < BB * SLEN_N; k += st) scores[k] = 0.f;
    for (int k = i; k < BB * L_N; k += st) fin_tok[k] = 0;
    for (int k = i; k < BB; k += st) { fin_sc[k] = NEGV; rmax_u[k] = 0u; }
}

// ---------------- exact scaled 2-way f16 split: x*4096 == h0 + h1 + O(2^-24 x) ----------------
__device__ __forceinline__ void split2(float x, _Float16& h0, _Float16& h1) {
    const float xs = x * 4096.f;       // exact (power of 2)
    h0 = (_Float16)xs;                 // RN
    const float r = xs - (float)h0;    // exact
    h1 = (_Float16)r;                  // RN
}

// Wsp layout: [((kt*2+p)*NPAD + col)*32 + kk]   (kt 0..31, p 0..1)
// Hsp layout: [((kt*2+p)*128  + row)*32 + kk]

// ---------------- once per call: pre-split W, K-tile-contiguous ----------------
__global__ __launch_bounds__(256) void k_wsplit(const float* __restrict__ W,
                                                _Float16* __restrict__ Wsp) {
    const int bid = blockIdx.x;
    const int ct = bid % 786, kt = bid / 786;
    const int n0 = ct * 64, k0 = kt * 32;
    const int tid = threadIdx.x;
    const int c = tid & 63, kk4 = tid >> 6;   // each thread: col c, k rows kk4*8..+7
    _Float16 v0[8], v1[8];
#pragma unroll
    for (int j = 0; j < 8; ++j) {
        const int k = kk4 * 8 + j;
        float wv = 0.f;
        if (n0 + c < VOCAB_N) wv = W[(size_t)(k0 + k) * VOCAB_N + n0 + c];
        split2(wv, v0[j], v1[j]);
    }
    const size_t base0 = ((size_t)(kt * 2 + 0) * NPAD + n0 + c) * 32 + kk4 * 8;
    const size_t base1 = ((size_t)(kt * 2 + 1) * NPAD + n0 + c) * 32 + kk4 * 8;
    *(f16x8*)&Wsp[base0] = *(f16x8*)v0;
    *(f16x8*)&Wsp[base1] = *(f16x8*)v1;
}

// ---------------- step-0 H split (steps 1+ fused into k_beam) ----------------
__global__ __launch_bounds__(256) void k_hsplit(const float* __restrict__ emb,
                                                const float* __restrict__ pos_emb,
                                                const int* __restrict__ tokens,
                                                _Float16* __restrict__ Hsp, int step) {
    const int row = blockIdx.x;           // 128
    const int tid = threadIdx.x;          // 256 -> 4 elems each
    const int tok = tokens[row * L_N + step];
    const int k4 = tid * 4;
    const int kt = k4 >> 5, kk = k4 & 31;
    const float4 e = *(const float4*)(emb + (size_t)tok * DIM + k4);
    const float4 p = *(const float4*)(pos_emb + (size_t)step * DIM + k4);
    const float hv[4] = {e.x + p.x, e.y + p.y, e.z + p.z, e.w + p.w};
    f16x4 o0, o1;
#pragma unroll
    for (int d = 0; d < 4; ++d) {
        _Float16 a0, a1;
        split2(hv[d], a0, a1);
        o0[d] = a0; o1[d] = a1;
    }
    *(f16x4*)&Hsp[((size_t)(kt * 2 + 0) * 128 + row) * 32 + kk] = o0;
    *(f16x4*)&Hsp[((size_t)(kt * 2 + 1) * 128 + row) * 32 + kk] = o1;
}

// ---------------- fast MFMA GEMM: contiguous staging + reg prefetch ----------------
__global__ __launch_bounds__(512) void k_gemm_fast(const _Float16* __restrict__ Wsp,
                                                   const _Float16* __restrict__ Hsp,
                                                   float* __restrict__ logits,
                                                   unsigned* __restrict__ rmax_u) {
    __shared__ __align__(16) _Float16 Ha[2][128][40];   // 20 KB
    __shared__ __align__(16) _Float16 Wb[2][128][40];   // 20 KB
    __shared__ unsigned smax[128];
    const int tid = threadIdx.x;
    const int n0 = blockIdx.x * 128;
    const int lane = tid & 63, wid = tid >> 6;
    const int la = lane & 15, g = lane >> 4;
    const int wr = wid >> 1, wc = wid & 1;              // wave: rows wr*32, cols wc*64
    const int sidx = tid >> 2, sg = tid & 3;            // staging: row tid>>2, kk (tid&3)*8

    if (tid < 128) smax[tid] = 0u;

    f32x4 acc[2][4];
#pragma unroll
    for (int mf = 0; mf < 2; ++mf)
#pragma unroll
        for (int nf = 0; nf < 4; ++nf)
#pragma unroll
            for (int j = 0; j < 4; ++j) acc[mf][nf][j] = 0.f;

    const size_t WT = (size_t)2 * NPAD * 32;            // halves per kt (both planes)
    const size_t wbase = (size_t)n0 * 32 + tid * 8;     // contiguous: thread tid -> 16B at tid*16
    const size_t hbase = (size_t)tid * 8;

    f16x8 rH0 = *(const f16x8*)&Hsp[hbase];
    f16x8 rH1 = *(const f16x8*)&Hsp[4096 + hbase];
    f16x8 rW0 = *(const f16x8*)&Wsp[wbase];
    f16x8 rW1 = *(const f16x8*)&Wsp[(size_t)NPAD * 32 + wbase];

    for (int t = 0; t < 32; ++t) {
        *(f16x8*)&Ha[0][sidx][sg * 8] = rH0;
        *(f16x8*)&Ha[1][sidx][sg * 8] = rH1;
        *(f16x8*)&Wb[0][sidx][sg * 8] = rW0;
        *(f16x8*)&Wb[1][sidx][sg * 8] = rW1;
        __syncthreads();
        if (t + 1 < 32) {
            const size_t ho = (size_t)(t + 1) * 8192;
            const size_t wo = (size_t)(t + 1) * WT;
            rH0 = *(const f16x8*)&Hsp[ho + hbase];
            rH1 = *(const f16x8*)&Hsp[ho + 4096 + hbase];
            rW0 = *(const f16x8*)&Wsp[wo + wbase];
            rW1 = *(const f16x8*)&Wsp[wo + (size_t)NPAD * 32 + wbase];
        }
        f16x8 a[2][2];
#pragma unroll
        for (int mf = 0; mf < 2; ++mf) {
            a[mf][0] = *(const f16x8*)&Ha[0][wr * 32 + mf * 16 + la][g * 8];
            a[mf][1] = *(const f16x8*)&Ha[1][wr * 32 + mf * 16 + la][g * 8];
        }
#pragma unroll
        for (int nf = 0; nf < 4; ++nf) {
            const int c = wc * 64 + nf * 16 + la;
            const f16x8 b0 = *(const f16x8*)&Wb[0][c][g * 8];
            const f16x8 b1 = *(const f16x8*)&Wb[1][c][g * 8];
#pragma unroll
            for (int mf = 0; mf < 2; ++mf) {
                f32x4 cc = acc[mf][nf];
                cc = __builtin_amdgcn_mfma_f32_16x16x32_f16(a[mf][0], b0, cc, 0, 0, 0);
                cc = __builtin_amdgcn_mfma_f32_16x16x32_f16(a[mf][0], b1, cc, 0, 0, 0);
                cc = __builtin_amdgcn_mfma_f32_16x16x32_f16(a[mf][1], b0, cc, 0, 0, 0);
                acc[mf][nf] = cc;
            }
        }
        __syncthreads();
    }

    // epilogue: unscale (exact 2^-24), store, row-max atomics
#pragma unroll
    for (int mf = 0; mf < 2; ++mf) {
        const int row = wr * 32 + mf * 16 + g * 4;
        float rmx[4] = {SENTV, SENTV, SENTV, SENTV};
#pragma unroll
        for (int nf = 0; nf < 4; ++nf) {
            const int col = n0 + wc * 64 + nf * 16 + la;
#pragma unroll
            for (int j = 0; j < 4; ++j) {
                const float v = acc[mf][nf][j] * 0x1p-24f;
                logits[(size_t)(row + j) * NPAD + col] = v;
                rmx[j] = fmaxf(rmx[j], v);
            }
        }
#pragma unroll
        for (int j = 0; j < 4; ++j) {
            float v = rmx[j];
            v = fmaxf(v, __shfl_xor(v, 1, 64));
            v = fmaxf(v, __shfl_xor(v, 2, 64));
            v = fmaxf(v, __shfl_xor(v, 4, 64));
            v = fmaxf(v, __shfl_xor(v, 8, 64));
            if (la == 0) atomicMax(&smax[row + j], sortable_f32(v));
        }
    }
    __syncthreads();
    if (tid < 128) atomicMax(&rmax_u[tid], smax[tid]);
}

// ---------------- slow-path GEMM (r11-proven, in-kernel split) ----------------
#define KT 32
__global__ __launch_bounds__(512) void k_gemm_slow(const float* __restrict__ W,
                                                   const float* __restrict__ emb,
                                                   const float* __restrict__ pos_emb,
                                                   const int* __restrict__ tokens,
                                                   float* __restrict__ logits,
                                                   unsigned* __restrict__ rmax_u, int step) {
    __shared__ __align__(16) _Float16 Ha[2][128][40];
    __shared__ __align__(16) _Float16 Wb[2][128][40];
    __shared__ unsigned smax[128];
    const int tid = threadIdx.x;
    const int n0 = blockIdx.x * 128;
    const bool full = (n0 + 128 <= VOCAB_N);
    const int lane = tid & 63, wid = tid >> 6;
    const int wr = wid >> 1, wc = wid & 1;
    const int la = lane & 15, g = lane >> 4;
    const int hrow = tid & 127, hkq = tid >> 7;
    const int tokH = tokens[hrow * L_N + step];
    const float* eprow = emb + (size_t)tokH * DIM;
    const float* pprow = pos_emb + (size_t)step * DIM;
    const int wcq = tid & 31, wk = tid >> 5;

    if (tid < 128) smax[tid] = 0u;

    f32x4 acc[2][4];
#pragma unroll
    for (int mf = 0; mf < 2; ++mf)
#pragma unroll
        for (int nf = 0; nf < 4; ++nf)
#pragma unroll
            for (int j = 0; j < 4; ++j) acc[mf][nf][j] = 0.f;

    for (int k0 = 0; k0 < DIM; k0 += KT) {
#pragma unroll
        for (int d = 0; d < 4; ++d) {
            const int c = wcq + 32 * d;
#pragma unroll
            for (int qq = 0; qq < 2; ++qq) {
                const int kk = wk + 16 * qq;
                float wv = 0.f;
                if (full || (n0 + c < VOCAB_N))
                    wv = W[(size_t)(k0 + kk) * VOCAB_N + n0 + c];
                _Float16 b0, b1;
                split2(wv, b0, b1);
                Wb[0][c][kk] = b0;
                Wb[1][c][kk] = b1;
            }
        }
#pragma unroll
        for (int qq = 0; qq < 2; ++qq) {
            const int kq = hkq + 4 * qq;
            const float4 e0 = *(const float4*)(eprow + k0 + kq * 4);
            const float4 p0 = *(const float4*)(pprow + k0 + kq * 4);
            const float hv[4] = {e0.x + p0.x, e0.y + p0.y, e0.z + p0.z, e0.w + p0.w};
            f16x4 o0, o1;
#pragma unroll
            for (int d = 0; d < 4; ++d) {
                _Float16 a0, a1;
                split2(hv[d], a0, a1);
                o0[d] = a0; o1[d] = a1;
            }
            *(f16x4*)&Ha[0][hrow][kq * 4] = o0;
            *(f16x4*)&Ha[1][hrow][kq * 4] = o1;
        }
        __syncthreads();
        f16x8 af[2][2];
#pragma unroll
        for (int mf = 0; mf < 2; ++mf)
#pragma unroll
            for (int p = 0; p < 2; ++p)
                af[mf][p] = *(const f16x8*)&Ha[p][wr * 32 + mf * 16 + la][g * 8];
#pragma unroll
        for (int nf = 0; nf < 4; ++nf) {
            const int c = wc * 64 + nf * 16 + la;
            const f16x8 b0 = *(const f16x8*)&Wb[0][c][g * 8];
            const f16x8 b1 = *(const f16x8*)&Wb[1][c][g * 8];
#pragma unroll
            for (int mf = 0; mf < 2; ++mf) {
                f32x4 cc = acc[mf][nf];
                cc = __builtin_amdgcn_mfma_f32_16x16x32_f16(af[mf][0], b0, cc, 0, 0, 0);
                cc = __builtin_amdgcn_mfma_f32_16x16x32_f16(af[mf][0], b1, cc, 0, 0, 0);
                cc = __builtin_amdgcn_mfma_f32_16x16x32_f16(af[mf][1], b0, cc, 0, 0, 0);
                acc[mf][nf] = cc;
            }
        }
        __syncthreads();
    }
#pragma unroll
    for (int mf = 0; mf < 2; ++mf) {
        const int row = wr * 32 + mf * 16 + g * 4;
        float rmx[4] = {SENTV, SENTV, SENTV, SENTV};
#pragma unroll
        for (int nf = 0; nf < 4; ++nf) {
            const int col = n0 + wc * 64 + nf * 16 + la;
#pragma unroll
            for (int j = 0; j < 4; ++j) {
                const float v = acc[mf][nf][j] * 0x1p-24f;
                logits[(size_t)(row + j) * NPAD + col] = v;
                rmx[j] = fmaxf(rmx[j], v);
            }
        }
#pragma unroll
        for (int j = 0; j < 4; ++j) {
            float v = rmx[j];
            v = fmaxf(v, __shfl_xor(v, 1, 64));
            v = fmaxf(v, __shfl_xor(v, 2, 64));
            v = fmaxf(v, __shfl_xor(v, 4, 64));
            v = fmaxf(v, __shfl_xor(v, 8, 64));
            if (la == 0) atomicMax(&smax[row + j], sortable_f32(v));
        }
    }
    __syncthreads();
    if (tid < 128) atomicMax(&rmax_u[tid], smax[tid]);
}

// ---------------- packed (x, idx) keys ----------------
__device__ __forceinline__ u64 pack_key(float x, int tk) {
    return ((u64)sortable_f32(x) << 32) | (unsigned)(VOCAB_N - tk);
}
__device__ __forceinline__ void insk16(u64 k, u64 lst[16]) {
#pragma unroll
    for (int p = 0; p < 16; ++p) {
        if (k > lst[p]) { u64 o = lst[p]; lst[p] = k; k = o; }
    }
}
__device__ __forceinline__ u64 wave_max_u64(u64 v) {
#pragma unroll
    for (int o = 32; o > 0; o >>= 1) {
        u64 w = __shfl_xor(v, o, 64);
        if (w > v) v = w;
    }
    return v;
}

// ---------------- fused per-quarter: top-16 (excl PAD) + numpy-exact pairwise exp-sum ----------------
#define RT2 256
__global__ __launch_bounds__(RT2) void k_scanexp(const float* __restrict__ logits,
                                                 const unsigned* __restrict__ rmax_u,
                                                 u64* __restrict__ htop,
                                                 float* __restrict__ qsum) {
    const int hb = blockIdx.x;            // 0..511
    const int row = hb >> 2, q = hb & 3;
    const int tid = threadIdx.x;
    const int lane = tid & 63, wid = tid >> 6;   // 4 waves
    const float* x = logits + (size_t)row * NPAD;
    const int lo = QLO[q], hi = QHI[q];
    const float mrow = unsort_f32(rmax_u[row]);

    u64 lst[16];
#pragma unroll
    for (int p = 0; p < 16; ++p) lst[p] = 0ULL;
    for (int v = lo + tid * 4; v + 3 < hi; v += RT2 * 4) {
        const float4 t = *(const float4*)(x + v);
        const float va[4] = {t.x, t.y, t.z, t.w};
#pragma unroll
        for (int u = 0; u < 4; ++u) {
            const int tk = v + u;
            if (tk == PAD_T) continue;
            const u64 key = pack_key(va[u], tk);
            if (key > lst[15]) insk16(key, lst);
        }
    }
    if (q == 3 && tid == 0) {             // tail element 50256
        const int tk = VOCAB_N - 1;
        const u64 key = pack_key(x[tk], tk);
        if (key > lst[15]) insk16(key, lst);
    }

    __shared__ u64 wtop[4][16];
    for (int pass = 0; pass < 16; ++pass) {
        const u64 cand = lst[0];
        const u64 mx = wave_max_u64(cand);
        const u64 ball = __ballot(cand == mx);
        const int first = __ffsll((u64)ball) - 1;
        if (lane == first) {
#pragma unroll
            for (int p = 0; p < 15; ++p) lst[p] = lst[p + 1];
            lst[15] = 0ULL;
        }
        if (lane == 0) wtop[wid][pass] = mx;
    }
    __syncthreads();

    __shared__ u64 sfin[16];
    if (tid < 64) {
        const u64 mine = wtop[tid >> 4][tid & 15];
        bool taken = false;
        for (int pass = 0; pass < 16; ++pass) {
            const u64 cand = taken ? 0ULL : mine;
            const u64 mx = wave_max_u64(cand);
            const u64 ball = __ballot(cand == mx);
            const int first = __ffsll((u64)ball) - 1;
            if (tid == first) taken = true;
            if (tid == 0) sfin[pass] = mx;
        }
    }

    const PWTree& T = (q == 0) ? g_q0 : (q == 1) ? g_q1 : (q == 2) ? g_q2 : g_q3;
    __shared__ float slot[512];
    for (int leaf = tid; leaf < T.nleaf; leaf += RT2) {
        const int s = T.lstart[leaf];
        const int n = T.lnum[leaf];
        float res;
        if (n < 8) {
            res = 0.f;
            for (int i = 0; i < n; ++i) res += expf(x[s + i] - mrow);
        } else {
            float r0 = expf(x[s + 0] - mrow), r1 = expf(x[s + 1] - mrow);
            float r2 = expf(x[s + 2] - mrow), r3 = expf(x[s + 3] - mrow);
            float r4 = expf(x[s + 4] - mrow), r5 = expf(x[s + 5] - mrow);
            float r6 = expf(x[s + 6] - mrow), r7 = expf(x[s + 7] - mrow);
            int i = 8;
            const int lim = n - (n & 7);
            for (; i < lim; i += 8) {
                r0 += expf(x[s + i + 0] - mrow); r1 += expf(x[s + i + 1] - mrow);
                r2 += expf(x[s + i + 2] - mrow); r3 += expf(x[s + i + 3] - mrow);
                r4 += expf(x[s + i + 4] - mrow); r5 += expf(x[s + i + 5] - mrow);
                r6 += expf(x[s + i + 6] - mrow); r7 += expf(x[s + i + 7] - mrow);
            }
            res = ((r0 + r1) + (r2 + r3)) + ((r4 + r5) + (r6 + r7));
            for (; i < n; ++i) res += expf(x[s + i] - mrow);
        }
        slot[T.lslot[leaf]] = res;
    }
    __syncthreads();
    for (int lev = 1; lev <= T.maxlev; ++lev) {
        for (int j = T.lvl[lev] + tid; j < T.lvl[lev + 1]; j += RT2)
            slot[T.eD[j]] = slot[T.eL[j]] + slot[T.eR[j]];
        __syncthreads();
    }
    if (tid == 0) qsum[hb] = slot[T.root];
    if (tid < 16) htop[hb * 16 + tid] = sfin[tid];
}

// ---------------- per-sentence: merge + top-8 + bookkeeping + fused next-step H split ----------------
__global__ __launch_bounds__(256) void k_beam(const u64* __restrict__ htop,
                                              unsigned* __restrict__ rmax_u,
                                              const float* __restrict__ qsum,
                                              int* __restrict__ tokens,
                                              float* __restrict__ scores,
                                              int* __restrict__ fin_tok,
                                              float* __restrict__ fin_sc,
                                              const float* __restrict__ emb,
                                              const float* __restrict__ pos_emb,
                                              _Float16* __restrict__ Hsp,
                                              int step) {
    const int sent = blockIdx.x;
    const int tid = threadIdx.x;
    const int rN = (step == 0) ? 1 : BEAM_N;

    __shared__ u64 keys[4][64];
    for (int e = tid; e < 256; e += 256) {
        const int r = e >> 6, i = e & 63;
        keys[r][i] = htop[((sent * BEAM_N + r) * 4 + (i >> 4)) * 16 + (i & 15)];
    }
    __syncthreads();

    __shared__ u64 merged[4][16];
    if (tid < 4) {
        int ia[4] = {0, 0, 0, 0};
        for (int o = 0; o < 16; ++o) {
            u64 best = 0ULL; int bq = 0;
#pragma unroll
            for (int qq = 0; qq < 4; ++qq) {
                const u64 h = (ia[qq] < 16) ? keys[tid][qq * 16 + ia[qq]] : 0ULL;
                if (h > best) { best = h; bq = qq; }
            }
            merged[tid][o] = best; ia[bq]++;
        }
    }
    __syncthreads();

    __shared__ float bval[64]; __shared__ int bflat[64];
    if (tid < 16 * rN) {
        const int r = tid >> 4, j = tid & 15;
        const int row = sent * BEAM_N + r;
        const float rm = unsort_f32(rmax_u[row]);
        const float rl = (float)log((double)((qsum[row * 4] + qsum[row * 4 + 1]) +
                                             (qsum[row * 4 + 2] + qsum[row * 4 + 3])));
        const float prev = (step == 0) ? 0.f : scores[row * SLEN_N + step - 1];
        const u64 k = merged[r][j];
        const float xv = unsort_f32((unsigned)(k >> 32));
        const int   tk = VOCAB_N - (int)(k & 0xFFFFFFFFu);
        bval[tid]  = ((xv - rm) - rl) + prev;   // exact ref association
        bflat[tid] = r * VOCAB_N + tk;
    }
    __syncthreads();
    __shared__ float cand_sc[8]; __shared__ int cand_flat[8];
    if (tid == 0) {
        const int nC = 16 * rN;
        for (int pass = 0; pass < 8; ++pass) {
            float bv = SENTV; int bi = 0x7fffffff; int bs = -1;
            for (int k = 0; k < nC; ++k) {
                const float v = bval[k]; const int ix = bflat[k];
                if (v > bv || (v == bv && ix < bi)) { bv = v; bi = ix; bs = k; }
            }
            cand_sc[pass] = bv; cand_flat[pass] = bi;
            bval[bs] = SENTV; bflat[bs] = 0x7fffffff;
        }
    }
    __syncthreads();

    __shared__ int   cur_tok[BEAM_N * L_N];
    __shared__ int   cur_fin[BEAM_N * L_N];
    __shared__ float cur_sc[BEAM_N * SLEN_N];
    for (int e = tid; e < BEAM_N * L_N; e += 256) {
        cur_tok[e] = tokens[sent * (BEAM_N * L_N) + e];
        cur_fin[e] = fin_tok[sent * (BEAM_N * L_N) + e];
    }
    for (int e = tid; e < BEAM_N * SLEN_N; e += 256)
        cur_sc[e] = scores[sent * (BEAM_N * SLEN_N) + e];
    __syncthreads();

    __shared__ int   tmp_fin[BEAM_N * L_N];
    __shared__ int   tmp_tok[BEAM_N * L_N];
    __shared__ float tmp_sc[BEAM_N * SLEN_N];
    __shared__ float nfin_s[BEAM_N];
    if (tid == 0) {
        int cb[8], ct[8];
#pragma unroll
        for (int j = 0; j < 8; ++j) {
            cb[j] = cand_flat[j] / VOCAB_N;
            ct[j] = cand_flat[j] % VOCAB_N;
        }
        float allsc[8];
#pragma unroll
        for (int j = 0; j < 4; ++j) allsc[j] = fin_sc[sent * BEAM_N + j];
#pragma unroll
        for (int j = 0; j < 4; ++j)
            allsc[4 + j] = (ct[j] == EOS_T) ? (cand_sc[j] / (float)(step + 1)) : NEGV;
        int fsel[4]; float nfin[4];
        bool used[8] = {false,false,false,false,false,false,false,false};
#pragma unroll
        for (int b = 0; b < 4; ++b) {
            int best = -1; float bvv = 0.f;
#pragma unroll
            for (int j = 0; j < 8; ++j) {
                if (used[j]) continue;
                if (best < 0 || allsc[j] > bvv) { best = j; bvv = allsc[j]; }
            }
            used[best] = true; fsel[b] = best; nfin[b] = bvv;
        }
#pragma unroll
        for (int b = 0; b < 4; ++b) {
            const int s = fsel[b];
            if (s < 4) {
                for (int p = 0; p < L_N; ++p) tmp_fin[b * L_N + p] = cur_fin[s * L_N + p];
            } else {
                const int bm = cb[s - 4];
                for (int p = 0; p < L_N; ++p)
                    tmp_fin[b * L_N + p] = (p == step + 1) ? EOS_T : cur_tok[bm * L_N + p];
            }
        }
        int ab[4], atk[4]; float asc[4]; int na = 0;
#pragma unroll
        for (int j = 0; j < 8; ++j) {
            if (na < 4 && ct[j] != EOS_T) { ab[na] = cb[j]; atk[na] = ct[j]; asc[na] = cand_sc[j]; ++na; }
        }
#pragma unroll
        for (int b = 0; b < 4; ++b) {
            const int bm = ab[b];
            for (int p = 0; p < L_N; ++p)
                tmp_tok[b * L_N + p] = (p == step + 1) ? atk[b] : cur_tok[bm * L_N + p];
            for (int p = 0; p < SLEN_N; ++p)
                tmp_sc[b * SLEN_N + p] = (p == step) ? asc[b] : cur_sc[bm * SLEN_N + p];
        }
#pragma unroll
        for (int b = 0; b < 4; ++b) nfin_s[b] = nfin[b];
    }
    __syncthreads();

    for (int e = tid; e < BEAM_N * L_N; e += 256) {
        fin_tok[sent * (BEAM_N * L_N) + e] = tmp_fin[e];
        tokens[sent * (BEAM_N * L_N) + e]  = tmp_tok[e];
    }
    for (int e = tid; e < BEAM_N * SLEN_N; e += 256)
        scores[sent * (BEAM_N * SLEN_N) + e] = tmp_sc[e];
    if (tid < 4) {
        fin_sc[sent * BEAM_N + tid] = nfin_s[tid];
        rmax_u[sent * BEAM_N + tid] = 0u;     // reset for next step
    }

    // ---- fused: pre-split H planes for step+1 (identical values to k_hsplit) ----
    {
        const int nstep = step + 1;
        const int r = tid >> 6;                       // 0..3
        const int row = sent * BEAM_N + r;
        const int tok = tmp_tok[r * L_N + nstep];
        const int kb = (tid & 63) * 16;               // 16 consecutive k
        const int kt = kb >> 5, kk0 = kb & 31;
        const float* ep = emb + (size_t)tok * DIM + kb;
        const float* pp = pos_emb + (size_t)nstep * DIM + kb;
        _Float16 v0[16], v1[16];
#pragma unroll
        for (int jj = 0; jj < 4; ++jj) {
            const float4 e = *(const float4*)(ep + jj * 4);
            const float4 p = *(const float4*)(pp + jj * 4);
            const float hv[4] = {e.x + p.x, e.y + p.y, e.z + p.z, e.w + p.w};
#pragma unroll
            for (int d = 0; d < 4; ++d)
                split2(hv[d], v0[jj * 4 + d], v1[jj * 4 + d]);
        }
        _Float16* d0 = &Hsp[((size_t)(kt * 2 + 0) * 128 + row) * 32 + kk0];
        _Float16* d1 = &Hsp[((size_t)(kt * 2 + 1) * 128 + row) * 32 + kk0];
        *(f16x8*)d0       = *(f16x8*)&v0[0];
        *(f16x8*)(d0 + 8) = *(f16x8*)&v0[8];
        *(f16x8*)d1       = *(f16x8*)&v1[0];
        *(f16x8*)(d1 + 8) = *(f16x8*)&v1[8];
    }
}

// ---------------- final forced-EOS merge + output write ----------------
__global__ __launch_bounds__(256) void k_final(const float* __restrict__ logits,
                                               const unsigned* __restrict__ rmax_u,
                                               const float* __restrict__ qsum,
                                               const int* __restrict__ tokens,
                                               const float* __restrict__ scores,
                                               const int* __restrict__ fin_tok,
                                               const float* __restrict__ fin_sc,
                                               float* __restrict__ out) {
    const int sent = blockIdx.x;
    const int tid = threadIdx.x;
    __shared__ int fsel_s[4]; __shared__ float nfin_s[4];
    if (tid == 0) {
        float allsc[8];
#pragma unroll
        for (int r = 0; r < 4; ++r) {
            const int row = sent * BEAM_N + r;
            const float rm = unsort_f32(rmax_u[row]);
            const float rl = (float)log((double)((qsum[row * 4] + qsum[row * 4 + 1]) +
                                                 (qsum[row * 4 + 2] + qsum[row * 4 + 3])));
            const float lpE = ((logits[(size_t)row * NPAD + EOS_T] - rm) - rl);
            allsc[r] = fin_sc[sent * BEAM_N + r];
            allsc[4 + r] = (scores[row * SLEN_N + (MAXLEN_N - 1)] + lpE) / 65.0f;
        }
        bool used[8] = {false,false,false,false,false,false,false,false};
#pragma unroll
        for (int b = 0; b < 4; ++b) {
            int best = -1; float bvv = 0.f;
#pragma unroll
            for (int j = 0; j < 8; ++j) {
                if (used[j]) continue;
                if (best < 0 || allsc[j] > bvv) { best = j; bvv = allsc[j]; }
            }
            used[best] = true; fsel_s[b] = best; nfin_s[b] = bvv;
        }
    }
    __syncthreads();
    for (int e = tid; e < BEAM_N * L_N; e += 256) {
        const int b = e / L_N, p = e % L_N;
        const int s = fsel_s[b]; int valt;
        if (s < 4) {
            valt = fin_tok[(sent * BEAM_N + s) * L_N + p];
        } else {
            const int r = s - 4;
            valt = (p == MAXLEN_N + 1) ? EOS_T : tokens[(sent * BEAM_N + r) * L_N + p];
        }
        out[(size_t)(sent * BEAM_N + b) * L_N + p] = (float)valt;
    }
    if (tid < 4) out[BSZ_N * BEAM_N * L_N + sent * BEAM_N + tid] = nfin_s[tid];
}

extern "C" void kernel_launch(void* const* d_in, const int* in_sizes, int n_in,
                              void* d_out, int out_size, void* d_ws, size_t ws_size,
                              hipStream_t stream) {
    const float* emb = (const float*)d_in[0];
    const float* W   = (const float*)d_in[1];
    const float* pos = (const float*)d_in[2];
    float* out = (float*)d_out;

    char* w = (char*)d_ws;
    size_t off = 0;
    auto alloc = [&](size_t bytes) { void* p = w + off; off += (bytes + 15) & ~(size_t)15; return p; };
    float*    logits = (float*)alloc((size_t)BB * NPAD * 4);
    unsigned* rmax_u = (unsigned*)alloc(BB * 4);
    float*    qsum   = (float*)alloc(BB * 4 * 4);
    u64*      htop   = (u64*)alloc((size_t)BB * 4 * 16 * 8);
    int*      tokens = (int*)alloc(BB * L_N * 4);
    float*    scores = (float*)alloc(BB * SLEN_N * 4);
    int*      ftok   = (int*)alloc(BB * L_N * 4);
    float*    fsc    = (float*)alloc(BB * 4);
    _Float16* Wsp    = (_Float16*)alloc((size_t)2 * NPAD * 1024 * 2);
    _Float16* Hsp    = (_Float16*)alloc((size_t)2 * 128 * 1024 * 2);
    const bool fast = (off <= ws_size);

    k_init<<<32, 256, 0, stream>>>(tokens, scores, ftok, fsc, rmax_u);
    if (fast) {
        k_wsplit<<<786 * 32, 256, 0, stream>>>(W, Wsp);
        k_hsplit<<<128, 256, 0, stream>>>(emb, pos, tokens, Hsp, 0);
    }
    for (int s = 0; s < MAXLEN_N; ++s) {
        if (fast) {
            k_gemm_fast<<<NPAD / 128, 512, 0, stream>>>(Wsp, Hsp, logits, rmax_u);
        } else {
            k_gemm_slow<<<NPAD / 128, 512, 0, stream>>>(W, emb, pos, tokens, logits, rmax_u, s);
        }
        k_scanexp<<<BB * 4, RT2, 0, stream>>>(logits, rmax_u, htop, qsum);
        k_beam<<<BSZ_N, 256, 0, stream>>>(htop, rmax_u, qsum, tokens, scores, ftok, fsc,
                                          emb, pos, Hsp, s);
    }
    if (fast) {
        k_gemm_fast<<<NPAD / 128, 512, 0, stream>>>(Wsp, Hsp, logits, rmax_u);
    } else {
        k_gemm_slow<<<NPAD / 128, 512, 0, stream>>>(W, emb, pos, tokens, logits, rmax_u, MAXLEN_N);
    }
    k_scanexp<<<BB * 4, RT2, 0, stream>>>(logits, rmax_u, htop, qsum);
    k_final<<<BSZ_N, 256, 0, stream>>>(logits, rmax_u, qsum, tokens, scores, ftok, fsc, out);
}